// Round 1
// baseline (1579.425 us; speedup 1.0000x reference)
//
#include <hip/hip_runtime.h>
#include <stdint.h>

#define DIM   1024
#define DEPTH 6
#define HEADS 16
#define FF    4096
#define SEQ   1024
#define BATCH 2
#define ROWS  (BATCH*SEQ)   // 2048
#define DH    64            // head dim

typedef __bf16 bf16x8 __attribute__((ext_vector_type(8)));
typedef float  f32x4  __attribute__((ext_vector_type(4)));

__device__ __forceinline__ unsigned short f2bf(float f) {
  unsigned int u = __builtin_bit_cast(unsigned int, f);
  u += 0x7fff + ((u >> 16) & 1);          // round-to-nearest-even
  return (unsigned short)(u >> 16);
}
__device__ __forceinline__ float bf2f(unsigned short h) {
  unsigned int u = ((unsigned int)h) << 16;
  return __builtin_bit_cast(float, u);
}

// async global->LDS, 16 bytes per lane. LDS dest must be uniform-base + lane*16.
__device__ __forceinline__ void async_load16(const void* g, void* l) {
  __builtin_amdgcn_global_load_lds(
      (const __attribute__((address_space(1))) unsigned int*)g,
      (__attribute__((address_space(3))) unsigned int*)l, 16, 0, 0);
}

// ---------------------------------------------------------------------------
// GEMM: C[M,N] = A[M,K] @ B^T  where B is stored [N][K] (bf16, K contiguous).
// BK=64, 256 threads (4 waves). 16x16x32 bf16 MFMA.
// LDS tiles XOR-swizzled: 16B chunk c of row r lives at chunk (c ^ (r&7)).
//
// NBUF=2: double-buffered LDS; prefetch of tile t+1 is issued BEFORE compute
//   of tile t, and the (compiler-emitted) vmcnt(0) drain sits at the single
//   __syncthreads() AFTER compute -> load latency hides under MFMA.
// NBUF=1: single-step path, requires K == BK (used for the scores GEMM).
//
// SPLITK>1: blockIdx.z is the K-split index; EPI==2 accumulates via atomicAdd
//   (bias added only by split 0). Otherwise blockIdx.z is the (batch,head) id.
//
// EPI: 0 = store bf16
//      1 = store bf16 of (acc*scale + bias2[zh][m][n])        (attn scores)
//      2 = Cf[m][n] += acc + bias1[n]                         (residual adds)
//      3 = store bf16 of gelu(acc + bias1[n])                 (FFN mid)
// ---------------------------------------------------------------------------
template<int BM, int BN, int EPI, int NBUF, int SPLITK, int MINW>
__global__ void __launch_bounds__(256, MINW)
gemm_kernel(const unsigned short* __restrict__ A, long lda,
            const unsigned short* __restrict__ B, long ldb,
            unsigned short* __restrict__ Cb, float* __restrict__ Cf, long ldc,
            const float* __restrict__ bias1, const float* __restrict__ bias2,
            float scale, int K, int ZH,
            long sAb, long sAh, long sBb, long sBh, long sCb, long sCh,
            long sBiasH)
{
  constexpr int BK = 64;                    // 8 chunks of 16B per row
  const int z = blockIdx.z;
  int zb = 0, zh = 0;
  long kbase = 0;
  int Kloc = K;
  if constexpr (SPLITK > 1) {
    Kloc  = K / SPLITK;
    kbase = (long)z * Kloc;
  } else {
    zb = z / ZH; zh = z % ZH;
    A += zb * sAb + zh * sAh;
    B += zb * sBb + zh * sBh;
  }
  const long coff = (long)zb * sCb + (long)zh * sCh;

  __shared__ unsigned short As[NBUF * BM * BK];
  __shared__ unsigned short Bs[NBUF * BN * BK];

  const int tid  = threadIdx.x;
  const int row0 = blockIdx.x * BM;
  const int col0 = blockIdx.y * BN;

  constexpr int WGN = 2;                    // waves along N
  constexpr int WGM = 2;                    // waves along M
  constexpr int WTM = BM / WGM;             // wave tile M
  constexpr int WTN = BN / WGN;             // wave tile N
  constexpr int ITM = WTM / 16;
  constexpr int ITN = WTN / 16;

  const int w = tid >> 6, l = tid & 63;
  const int quad = l >> 4, r16 = l & 15;
  const int wm = (w / WGN) * WTM;
  const int wn = (w % WGN) * WTN;
  const int sw = r16 & 7;                   // read-side XOR swizzle key

  f32x4 acc[ITM][ITN] = {};

  constexpr int APASS = (BM * 8) / 256;     // 16B chunks per thread for A tile
  constexpr int BPASS = (BN * 8) / 256;

  const unsigned short* Ag = A + (long)row0 * lda;
  const unsigned short* Bg = B + (long)col0 * ldb;

  auto stage = [&](int buf, long k0) {
    unsigned short* Asb = &As[buf * (BM * BK)];
    unsigned short* Bsb = &Bs[buf * (BN * BK)];
#pragma unroll
    for (int p = 0; p < APASS; p++) {
      int flat = p * 256 + tid;
      int r = flat >> 3, cl = flat & 7;
      int cg = cl ^ (r & 7);                // fetch the chunk that belongs at slot cl
      async_load16(Ag + (long)r * lda + k0 + cg * 8, &Asb[flat * 8]);
    }
#pragma unroll
    for (int p = 0; p < BPASS; p++) {
      int flat = p * 256 + tid;
      int r = flat >> 3, cl = flat & 7;
      int cg = cl ^ (r & 7);
      async_load16(Bg + (long)r * ldb + k0 + cg * 8, &Bsb[flat * 8]);
    }
  };

  auto compute = [&](int buf) {
    const unsigned short* Asb = &As[buf * (BM * BK)];
    const unsigned short* Bsb = &Bs[buf * (BN * BK)];
#pragma unroll
    for (int ks = 0; ks < 2; ks++) {
      const int c = ks * 4 + quad;          // logical 16B chunk index
      bf16x8 af[ITM], bfr[ITN];
#pragma unroll
      for (int i = 0; i < ITM; i++)
        af[i] = *(const bf16x8*)&Asb[(wm + i * 16 + r16) * BK + (c ^ sw) * 8];
#pragma unroll
      for (int j = 0; j < ITN; j++)
        bfr[j] = *(const bf16x8*)&Bsb[(wn + j * 16 + r16) * BK + (c ^ sw) * 8];
#pragma unroll
      for (int i = 0; i < ITM; i++)
#pragma unroll
        for (int j = 0; j < ITN; j++)
          acc[i][j] = __builtin_amdgcn_mfma_f32_16x16x32_bf16(af[i], bfr[j], acc[i][j], 0, 0, 0);
    }
  };

  if constexpr (NBUF == 1) {
    // single K-step path (K == BK): identical to the old structure
    stage(0, kbase);
    __syncthreads();                        // drains vmcnt
    compute(0);
  } else {
    // double-buffered pipeline: prefetch t+1 before compute(t); the single
    // barrier (with its implicit vmcnt(0) drain) sits AFTER compute.
    stage(0, kbase);
    __syncthreads();
    int cur = 0;
    for (long k0 = kbase + BK; k0 < kbase + Kloc; k0 += BK) {
      stage(cur ^ 1, k0);                   // issue next-tile loads (async)
      compute(cur);                         // MFMA on current tile
      __syncthreads();                      // vmcnt(0)+barrier: next tile ready
      cur ^= 1;
    }
    compute(cur);                           // last tile, no prefetch
  }

  // epilogue: C/D layout row = quad*4 + reg, col = lane&15
#pragma unroll
  for (int i = 0; i < ITM; i++) {
#pragma unroll
    for (int j = 0; j < ITN; j++) {
      const int rr = row0 + wm + i * 16 + quad * 4;
      const int cc = col0 + wn + j * 16 + r16;
#pragma unroll
      for (int r = 0; r < 4; r++) {
        const long idx = (long)(rr + r) * ldc + cc;
        float v = acc[i][j][r];
        if constexpr (EPI == 0) {
          Cb[coff + idx] = f2bf(v);
        } else if constexpr (EPI == 1) {
          v = v * scale + bias2[(long)zh * sBiasH + idx];
          Cb[coff + idx] = f2bf(v);
        } else if constexpr (EPI == 2) {
          if constexpr (SPLITK > 1) {
            float add = v + (z == 0 ? bias1[cc] : 0.0f);
            atomicAdd(&Cf[coff + idx], add);
          } else {
            Cf[coff + idx] += v + bias1[cc];
          }
        } else if constexpr (EPI == 3) {
          v += bias1[cc];
          float gl = 0.5f * v * (1.0f + erff(v * 0.70710678118654752f));
          Cb[coff + idx] = f2bf(gl);
        }
      }
    }
  }
}

// ---------------------------------------------------------------------------
// LayerNorm: one block (256 thr) per row of 1024 fp32 -> bf16 out
// ---------------------------------------------------------------------------
__global__ void k_layernorm(const float* __restrict__ x, const float* __restrict__ g,
                            const float* __restrict__ b, unsigned short* __restrict__ out)
{
  const int row = blockIdx.x;
  const int t = threadIdx.x;
  float4 v = ((const float4*)(x + (long)row * DIM))[t];
  float s = v.x + v.y + v.z + v.w;
  float q = v.x * v.x + v.y * v.y + v.z * v.z + v.w * v.w;
#pragma unroll
  for (int off = 32; off > 0; off >>= 1) {
    s += __shfl_down(s, off);
    q += __shfl_down(q, off);
  }
  __shared__ float shs[4], shq[4];
  if ((t & 63) == 0) { shs[t >> 6] = s; shq[t >> 6] = q; }
  __syncthreads();
  s = shs[0] + shs[1] + shs[2] + shs[3];
  q = shq[0] + shq[1] + shq[2] + shq[3];
  const float mu  = s * (1.0f / DIM);
  const float var = q * (1.0f / DIM) - mu * mu;
  const float rs  = rsqrtf(var + 1e-5f);
  float4 gg = ((const float4*)g)[t];
  float4 bb = ((const float4*)b)[t];
  ushort4 o;
  o.x = f2bf((v.x - mu) * rs * gg.x + bb.x);
  o.y = f2bf((v.y - mu) * rs * gg.y + bb.y);
  o.z = f2bf((v.z - mu) * rs * gg.z + bb.z);
  o.w = f2bf((v.w - mu) * rs * gg.w + bb.w);
  ((ushort4*)out)[(long)row * (DIM / 4) + t] = o;
}

// ---------------------------------------------------------------------------
// Row softmax over 1024 bf16, in place. One block per row.
// ---------------------------------------------------------------------------
__global__ void k_softmax(unsigned short* __restrict__ S)
{
  const long row = blockIdx.x;
  unsigned short* sr = S + row * SEQ;
  const int t = threadIdx.x;
  ushort4 u = ((ushort4*)sr)[t];
  float a0 = bf2f(u.x), a1 = bf2f(u.y), a2 = bf2f(u.z), a3 = bf2f(u.w);
  float mx = fmaxf(fmaxf(a0, a1), fmaxf(a2, a3));
#pragma unroll
  for (int off = 32; off > 0; off >>= 1) mx = fmaxf(mx, __shfl_down(mx, off));
  __shared__ float sh[4];
  if ((t & 63) == 0) sh[t >> 6] = mx;
  __syncthreads();
  mx = fmaxf(fmaxf(sh[0], sh[1]), fmaxf(sh[2], sh[3]));
  __syncthreads();
  float e0 = __expf(a0 - mx), e1 = __expf(a1 - mx), e2 = __expf(a2 - mx), e3 = __expf(a3 - mx);
  float s = e0 + e1 + e2 + e3;
#pragma unroll
  for (int off = 32; off > 0; off >>= 1) s += __shfl_down(s, off);
  if ((t & 63) == 0) sh[t >> 6] = s;
  __syncthreads();
  s = sh[0] + sh[1] + sh[2] + sh[3];
  const float inv = 1.0f / s;
  u.x = f2bf(e0 * inv); u.y = f2bf(e1 * inv); u.z = f2bf(e2 * inv); u.w = f2bf(e3 * inv);
  ((ushort4*)sr)[t] = u;
}

// ---------------------------------------------------------------------------
// Weight transpose+convert: w[K][N] fp32 -> wT[N][K] bf16. block (64,4), tile 64x64.
// ---------------------------------------------------------------------------
__global__ void k_wtrans(const float* __restrict__ w, unsigned short* __restrict__ wT,
                         int K, int N)
{
  __shared__ unsigned short tile[64][65];
  const int n0 = blockIdx.x * 64, k0 = blockIdx.y * 64;
  const int tx = threadIdx.x, ty = threadIdx.y;
#pragma unroll
  for (int i = 0; i < 16; i++)
    tile[ty + 4 * i][tx] = f2bf(w[(long)(k0 + ty + 4 * i) * N + n0 + tx]);
  __syncthreads();
#pragma unroll
  for (int i = 0; i < 16; i++)
    wT[(long)(n0 + ty + 4 * i) * K + k0 + tx] = tile[tx][ty + 4 * i];
}

// ---------------------------------------------------------------------------
// V transpose: qkv[b, n, 2*DIM + h*64 + d] (bf16) -> vT[(b*16+h)][d][n]
// ---------------------------------------------------------------------------
__global__ void k_vtrans(const unsigned short* __restrict__ qkv, unsigned short* __restrict__ vT)
{
  __shared__ unsigned short tile[64][65];
  const int z = blockIdx.z;
  const int b_ = z >> 4, h_ = z & 15;
  const int n0 = blockIdx.x * 64;
  const int tx = threadIdx.x, ty = threadIdx.y;
  const unsigned short* src = qkv + (long)b_ * SEQ * (3 * DIM) + 2 * DIM + h_ * DH;
#pragma unroll
  for (int i = 0; i < 16; i++)
    tile[ty + 4 * i][tx] = src[(long)(n0 + ty + 4 * i) * (3 * DIM) + tx];
  __syncthreads();
  unsigned short* dst = vT + (long)z * DH * SEQ;
#pragma unroll
  for (int i = 0; i < 16; i++)
    dst[(long)(ty + 4 * i) * SEQ + n0 + tx] = tile[tx][ty + 4 * i];
}

// ---------------------------------------------------------------------------
extern "C" void kernel_launch(void* const* d_in, const int* in_sizes, int n_in,
                              void* d_out, int out_size, void* d_ws, size_t ws_size,
                              hipStream_t stream)
{
  const float* x0   = (const float*)d_in[0];
  const float* rpb  = (const float*)d_in[1];
  const float* ln1g = (const float*)d_in[2];
  const float* ln1b = (const float*)d_in[3];
  const float* wqkv = (const float*)d_in[4];
  const float* wout = (const float*)d_in[5];
  const float* bout = (const float*)d_in[6];
  const float* ln2g = (const float*)d_in[7];
  const float* ln2b = (const float*)d_in[8];
  const float* w1   = (const float*)d_in[9];
  const float* b1   = (const float*)d_in[10];
  const float* w2   = (const float*)d_in[11];
  const float* b2   = (const float*)d_in[12];
  float* x = (float*)d_out;   // running residual stream (fp32), doubles as output

  // workspace layout (~128 MB total)
  char* p = (char*)d_ws;
  auto alloc = [&](size_t n) { char* r = p; p += (n + 255) & ~(size_t)255; return r; };
  unsigned short* wTqkv = (unsigned short*)alloc((size_t)3 * DIM * DIM * 2);
  unsigned short* wTout = (unsigned short*)alloc((size_t)DIM * DIM * 2);
  unsigned short* wT1   = (unsigned short*)alloc((size_t)FF * DIM * 2);
  unsigned short* wT2   = (unsigned short*)alloc((size_t)DIM * FF * 2);
  unsigned short* hbuf  = (unsigned short*)alloc((size_t)ROWS * DIM * 2);
  unsigned short* qkvb  = (unsigned short*)alloc((size_t)ROWS * 3 * DIM * 2);
  unsigned short* Sbuf  = (unsigned short*)alloc((size_t)BATCH * HEADS * SEQ * SEQ * 2);
  unsigned short* vTb   = (unsigned short*)alloc((size_t)BATCH * HEADS * DH * SEQ * 2);
  unsigned short* obuf  = (unsigned short*)alloc((size_t)ROWS * DIM * 2);
  unsigned short* ffnb  = (unsigned short*)alloc((size_t)ROWS * FF * 2);

  hipMemcpyAsync(x, x0, (size_t)ROWS * DIM * 4, hipMemcpyDeviceToDevice, stream);

  const dim3 tb(64, 4);
  for (int l = 0; l < DEPTH; l++) {
    const float* Wqkv = wqkv + (size_t)l * DIM * 3 * DIM;
    const float* Wout = wout + (size_t)l * DIM * DIM;
    const float* W1   = w1   + (size_t)l * DIM * FF;
    const float* W2   = w2   + (size_t)l * FF * DIM;

    k_wtrans<<<dim3(3 * DIM / 64, DIM / 64), tb, 0, stream>>>(Wqkv, wTqkv, DIM, 3 * DIM);
    k_wtrans<<<dim3(DIM / 64, DIM / 64),     tb, 0, stream>>>(Wout, wTout, DIM, DIM);
    k_wtrans<<<dim3(FF / 64, DIM / 64),      tb, 0, stream>>>(W1,   wT1,   DIM, FF);
    k_wtrans<<<dim3(DIM / 64, FF / 64),      tb, 0, stream>>>(W2,   wT2,   FF, DIM);

    // ---- attention ----
    k_layernorm<<<ROWS, 256, 0, stream>>>(x, ln1g + l * DIM, ln1b + l * DIM, hbuf);

    // qkv: 64x128 tiles -> 32*24 = 768 blocks (dbuf, 48KB LDS, 3 blk/CU)
    gemm_kernel<64, 128, 0, 2, 1, 4><<<dim3(ROWS / 64, 3 * DIM / 128, 1), 256, 0, stream>>>(
        hbuf, DIM, wTqkv, DIM, qkvb, nullptr, 3 * DIM, nullptr, nullptr, 1.0f, DIM,
        1, 0, 0, 0, 0, 0, 0, 0);

    // scores: per (b,h): q[n,64] @ k[n,64]^T * 0.125 + rpb[h] -> bf16 S
    // K=64 = single K-step: single-buffer path (NBUF=1), 2048 blocks
    gemm_kernel<128, 128, 1, 1, 1, 4><<<dim3(SEQ / 128, SEQ / 128, BATCH * HEADS), 256, 0, stream>>>(
        qkvb, 3 * DIM, qkvb + DIM, 3 * DIM, Sbuf, nullptr, SEQ, nullptr, rpb, 0.125f, DH,
        HEADS, (long)SEQ * 3 * DIM, DH, (long)SEQ * 3 * DIM, DH,
        (long)HEADS * SEQ * SEQ, (long)SEQ * SEQ, (long)SEQ * SEQ);

    k_softmax<<<BATCH * HEADS * SEQ, 256, 0, stream>>>(Sbuf);

    k_vtrans<<<dim3(SEQ / 64, 1, BATCH * HEADS), tb, 0, stream>>>(qkvb, vTb);

    // o = P @ v : 64x64 tiles (dbuf) -> 512 blocks
    gemm_kernel<64, 64, 0, 2, 1, 4><<<dim3(SEQ / 64, 1, BATCH * HEADS), 256, 0, stream>>>(
        Sbuf, SEQ, vTb, SEQ, obuf, nullptr, DIM, nullptr, nullptr, 1.0f, SEQ,
        HEADS, (long)HEADS * SEQ * SEQ, (long)SEQ * SEQ,
        (long)HEADS * DH * SEQ, (long)DH * SEQ, (long)SEQ * DIM, (long)DH, 0);

    // x += o @ w_out + b_out : 64x64, split-K=2 -> 1024 blocks (4 blk/CU), atomic acc
    gemm_kernel<64, 64, 2, 2, 2, 4><<<dim3(ROWS / 64, DIM / 64, 2), 256, 0, stream>>>(
        obuf, DIM, wTout, DIM, nullptr, x, DIM, bout + l * DIM, nullptr, 1.0f, DIM,
        1, 0, 0, 0, 0, 0, 0, 0);

    // ---- FFN ----
    k_layernorm<<<ROWS, 256, 0, stream>>>(x, ln2g + l * DIM, ln2b + l * DIM, hbuf);

    // FFN1: 128x128 (dbuf, 64KB LDS, 2 blk/CU; MINW=2 to avoid spill) -> 512 blocks
    gemm_kernel<128, 128, 3, 2, 1, 2><<<dim3(ROWS / 128, FF / 128, 1), 256, 0, stream>>>(
        hbuf, DIM, wT1, DIM, ffnb, nullptr, FF, b1 + l * FF, nullptr, 1.0f, DIM,
        1, 0, 0, 0, 0, 0, 0, 0);

    // FFN2: 64x64, split-K=2 over K=4096 -> 1024 blocks (4 blk/CU), atomic acc
    gemm_kernel<64, 64, 2, 2, 2, 4><<<dim3(ROWS / 64, DIM / 64, 2), 256, 0, stream>>>(
        ffnb, FF, wT2, FF, nullptr, x, DIM, b2 + l * DIM, nullptr, 1.0f, FF,
        1, 0, 0, 0, 0, 0, 0, 0);
  }
}

// Round 2
// 1359.499 us; speedup vs baseline: 1.1618x; 1.1618x over previous
//
#include <hip/hip_runtime.h>
#include <stdint.h>

#define DIM   1024
#define DEPTH 6
#define HEADS 16
#define FF    4096
#define SEQ   1024
#define BATCH 2
#define ROWS  (BATCH*SEQ)   // 2048
#define DH    64            // head dim

typedef __bf16 bf16x8 __attribute__((ext_vector_type(8)));
typedef float  f32x4  __attribute__((ext_vector_type(4)));

__device__ __forceinline__ unsigned short f2bf(float f) {
  unsigned int u = __builtin_bit_cast(unsigned int, f);
  u += 0x7fff + ((u >> 16) & 1);          // round-to-nearest-even
  return (unsigned short)(u >> 16);
}
__device__ __forceinline__ float bf2f(unsigned short h) {
  unsigned int u = ((unsigned int)h) << 16;
  return __builtin_bit_cast(float, u);
}

// async global->LDS, 16 bytes per lane. LDS dest must be uniform-base + lane*16.
__device__ __forceinline__ void async_load16(const void* g, void* l) {
  __builtin_amdgcn_global_load_lds(
      (const __attribute__((address_space(1))) unsigned int*)g,
      (__attribute__((address_space(3))) unsigned int*)l, 16, 0, 0);
}

// ---------------------------------------------------------------------------
// GEMM: C[M,N] = A[M,K] @ B^T  where B is stored [N][K] (bf16, K contiguous).
// BK=64, 256 threads (4 waves). 16x16x32 bf16 MFMA.
// LDS tiles XOR-swizzled: 16B chunk c of row r lives at chunk (c ^ (r&7)).
// NBUF=2: double-buffered LDS; prefetch of tile t+1 issued BEFORE compute of
//   tile t; the single __syncthreads() (with its implicit vmcnt(0) drain) sits
//   AFTER compute -> load latency hides under MFMA.
// EPI: 0 = store bf16
//      2 = Cf[m][n] += acc + bias1[n]                         (residual adds)
//      3 = store bf16 of gelu(acc + bias1[n])                 (FFN mid)
// ---------------------------------------------------------------------------
template<int BM, int BN, int EPI, int NBUF, int MINW>
__global__ void __launch_bounds__(256, MINW)
gemm_kernel(const unsigned short* __restrict__ A, long lda,
            const unsigned short* __restrict__ B, long ldb,
            unsigned short* __restrict__ Cb, float* __restrict__ Cf, long ldc,
            const float* __restrict__ bias1, float scale, int K)
{
  constexpr int BK = 64;                    // 8 chunks of 16B per row
  __shared__ unsigned short As[NBUF * BM * BK];
  __shared__ unsigned short Bs[NBUF * BN * BK];

  const int tid  = threadIdx.x;
  const int row0 = blockIdx.x * BM;
  const int col0 = blockIdx.y * BN;

  constexpr int WGN = 2;                    // waves along N
  constexpr int WGM = 2;                    // waves along M
  constexpr int WTM = BM / WGM;             // wave tile M
  constexpr int WTN = BN / WGN;             // wave tile N
  constexpr int ITM = WTM / 16;
  constexpr int ITN = WTN / 16;

  const int w = tid >> 6, l = tid & 63;
  const int quad = l >> 4, r16 = l & 15;
  const int wm = (w / WGN) * WTM;
  const int wn = (w % WGN) * WTN;
  const int sw = r16 & 7;                   // read-side XOR swizzle key

  f32x4 acc[ITM][ITN] = {};

  constexpr int APASS = (BM * 8) / 256;     // 16B chunks per thread for A tile
  constexpr int BPASS = (BN * 8) / 256;

  const unsigned short* Ag = A + (long)row0 * lda;
  const unsigned short* Bg = B + (long)col0 * ldb;

  auto stage = [&](int buf, long k0) {
    unsigned short* Asb = &As[buf * (BM * BK)];
    unsigned short* Bsb = &Bs[buf * (BN * BK)];
#pragma unroll
    for (int p = 0; p < APASS; p++) {
      int flat = p * 256 + tid;
      int r = flat >> 3, cl = flat & 7;
      int cg = cl ^ (r & 7);                // fetch the chunk that belongs at slot cl
      async_load16(Ag + (long)r * lda + k0 + cg * 8, &Asb[flat * 8]);
    }
#pragma unroll
    for (int p = 0; p < BPASS; p++) {
      int flat = p * 256 + tid;
      int r = flat >> 3, cl = flat & 7;
      int cg = cl ^ (r & 7);
      async_load16(Bg + (long)r * ldb + k0 + cg * 8, &Bsb[flat * 8]);
    }
  };

  auto compute = [&](int buf) {
    const unsigned short* Asb = &As[buf * (BM * BK)];
    const unsigned short* Bsb = &Bs[buf * (BN * BK)];
#pragma unroll
    for (int ks = 0; ks < 2; ks++) {
      const int c = ks * 4 + quad;          // logical 16B chunk index
      bf16x8 af[ITM], bfr[ITN];
#pragma unroll
      for (int i = 0; i < ITM; i++)
        af[i] = *(const bf16x8*)&Asb[(wm + i * 16 + r16) * BK + (c ^ sw) * 8];
#pragma unroll
      for (int j = 0; j < ITN; j++)
        bfr[j] = *(const bf16x8*)&Bsb[(wn + j * 16 + r16) * BK + (c ^ sw) * 8];
#pragma unroll
      for (int i = 0; i < ITM; i++)
#pragma unroll
        for (int j = 0; j < ITN; j++)
          acc[i][j] = __builtin_amdgcn_mfma_f32_16x16x32_bf16(af[i], bfr[j], acc[i][j], 0, 0, 0);
    }
  };

  if constexpr (NBUF == 1) {
    stage(0, 0);
    __syncthreads();
    compute(0);
  } else {
    stage(0, 0);
    __syncthreads();
    int cur = 0;
    for (long k0 = BK; k0 < K; k0 += BK) {
      stage(cur ^ 1, k0);                   // issue next-tile loads (async)
      compute(cur);                         // MFMA on current tile
      __syncthreads();                      // vmcnt(0)+barrier: next tile ready
      cur ^= 1;
    }
    compute(cur);                           // last tile, no prefetch
  }

  // epilogue: C/D layout row = quad*4 + reg, col = lane&15
#pragma unroll
  for (int i = 0; i < ITM; i++) {
#pragma unroll
    for (int j = 0; j < ITN; j++) {
      const int rr = row0 + wm + i * 16 + quad * 4;
      const int cc = col0 + wn + j * 16 + r16;
#pragma unroll
      for (int r = 0; r < 4; r++) {
        const long idx = (long)(rr + r) * ldc + cc;
        float v = acc[i][j][r];
        if constexpr (EPI == 0) {
          Cb[idx] = f2bf(v);
        } else if constexpr (EPI == 2) {
          Cf[idx] += v + bias1[cc];
        } else if constexpr (EPI == 3) {
          v += bias1[cc];
          float gl = 0.5f * v * (1.0f + erff(v * 0.70710678118654752f));
          Cb[idx] = f2bf(gl);
        }
      }
    }
  }
}

// ---------------------------------------------------------------------------
// Fused flash attention.
// Grid: (SEQ/64, 1, BATCH*HEADS), 256 threads (4 waves).
// Per block: 64 Q-rows of one (b,h). Wave w owns Q rows [w*16, w*16+16).
// Loop over 16 key-tiles of 64: S = Q@K^T*0.125 + rpb (fp32), online softmax,
// P (bf16, via wave-private swizzled LDS) @ V^T accumulated in fp32.
// K/V^T tiles double-buffered (async_load16), one barrier per tile.
// ---------------------------------------------------------------------------
__global__ void __launch_bounds__(256, 2)
k_flashattn(const unsigned short* __restrict__ qkv,  // [b][n][3*DIM]
            const unsigned short* __restrict__ vT,   // [b*16+h][d][n]
            const float* __restrict__ rpb,           // [h][n][n]
            unsigned short* __restrict__ O)          // [b][n][DIM]
{
  constexpr int QT = 64;          // q rows per block
  constexpr int KT = 64;          // keys per tile
  constexpr int NT = SEQ / KT;    // 16 tiles

  __shared__ __align__(16) unsigned short Qs[QT * DH];       // 8 KB
  __shared__ __align__(16) unsigned short Ks[2][KT * DH];    // 16 KB
  __shared__ __align__(16) unsigned short Vs[2][DH * KT];    // 16 KB
  __shared__ __align__(16) unsigned short Ps[4][16 * KT];    // 8 KB (per-wave)

  const int z = blockIdx.z;
  const int b_ = z >> 4, h_ = z & 15;
  const int q0 = blockIdx.x * QT;
  const int tid = threadIdx.x;
  const int w = tid >> 6, l = tid & 63;
  const int quad = l >> 4, r16 = l & 15;
  const int sw = r16 & 7;

  const unsigned short* Qg = qkv + (long)b_ * SEQ * (3 * DIM) + h_ * DH;
  const unsigned short* Kg = Qg + DIM;
  const unsigned short* Vg = vT + (long)z * DH * SEQ;
  const float* Rg = rpb + (long)h_ * SEQ * SEQ + (long)q0 * SEQ;

  auto stageKV = [&](int buf, int kt) {
#pragma unroll
    for (int p = 0; p < 2; p++) {
      int flat = p * 256 + tid;
      int r = flat >> 3, cl = flat & 7, cg = cl ^ (r & 7);
      async_load16(Kg + (long)(kt * KT + r) * (3 * DIM) + cg * 8, &Ks[buf][flat * 8]);
    }
#pragma unroll
    for (int p = 0; p < 2; p++) {
      int flat = p * 256 + tid;
      int r = flat >> 3, cl = flat & 7, cg = cl ^ (r & 7);
      async_load16(Vg + (long)r * SEQ + kt * KT + cg * 8, &Vs[buf][flat * 8]);
    }
  };

  // stage Q + first K/V
#pragma unroll
  for (int p = 0; p < 2; p++) {
    int flat = p * 256 + tid;
    int r = flat >> 3, cl = flat & 7, cg = cl ^ (r & 7);
    async_load16(Qg + (long)(q0 + r) * (3 * DIM) + cg * 8, &Qs[flat * 8]);
  }
  stageKV(0, 0);
  __syncthreads();

  // Q fragments (held in registers for the whole kernel)
  bf16x8 qA[2];
#pragma unroll
  for (int ks = 0; ks < 2; ks++)
    qA[ks] = *(const bf16x8*)&Qs[(w * 16 + r16) * DH + (((ks * 4 + quad)) ^ sw) * 8];

  f32x4 Oacc[4] = {};
  float m[4], lsum[4];
#pragma unroll
  for (int r = 0; r < 4; r++) { m[r] = -1e30f; lsum[r] = 0.0f; }

  int cur = 0;
  for (int kt = 0; kt < NT; kt++) {
    if (kt + 1 < NT) stageKV(cur ^ 1, kt + 1);   // async prefetch next tile

    // rpb bias loads (global fp32) — issued before MFMAs so they overlap
    float bias[4][4];
    const float* Rt = Rg + kt * KT;
#pragma unroll
    for (int j = 0; j < 4; j++)
#pragma unroll
      for (int r = 0; r < 4; r++)
        bias[j][r] = Rt[(long)(w * 16 + quad * 4 + r) * SEQ + j * 16 + r16];

    // S = Q @ K^T  (rows = q, cols = keys of this tile)
    f32x4 s[4] = {};
#pragma unroll
    for (int ks = 0; ks < 2; ks++) {
      bf16x8 kB[4];
#pragma unroll
      for (int j = 0; j < 4; j++)
        kB[j] = *(const bf16x8*)&Ks[cur][(j * 16 + r16) * DH + ((ks * 4 + quad) ^ sw) * 8];
#pragma unroll
      for (int j = 0; j < 4; j++)
        s[j] = __builtin_amdgcn_mfma_f32_16x16x32_bf16(qA[ks], kB[j], s[j], 0, 0, 0);
    }

    // scores in fp32 + online softmax. Row of C-layout = quad*4+r; its 64
    // tile-scores live in 4 frags (j) x 16 lanes (r16) -> reduce over j then
    // shuffle-xor 1,2,4,8 (stays within the 16-lane quad group).
    float sc[4][4], p_[4][4], mt[4], ts[4];
#pragma unroll
    for (int j = 0; j < 4; j++)
#pragma unroll
      for (int r = 0; r < 4; r++)
        sc[j][r] = s[j][r] * 0.125f + bias[j][r];
#pragma unroll
    for (int r = 0; r < 4; r++) {
      mt[r] = fmaxf(fmaxf(sc[0][r], sc[1][r]), fmaxf(sc[2][r], sc[3][r]));
#pragma unroll
      for (int msk = 1; msk < 16; msk <<= 1)
        mt[r] = fmaxf(mt[r], __shfl_xor(mt[r], msk));
      float mn = fmaxf(m[r], mt[r]);
      float scale = __expf(m[r] - mn);
      m[r] = mn;
#pragma unroll
      for (int j = 0; j < 4; j++) {
        p_[j][r] = __expf(sc[j][r] - mn);
        Oacc[j][r] *= scale;
      }
      ts[r] = p_[0][r] + p_[1][r] + p_[2][r] + p_[3][r];
#pragma unroll
      for (int msk = 1; msk < 16; msk <<= 1)
        ts[r] += __shfl_xor(ts[r], msk);
      lsum[r] = lsum[r] * scale + ts[r];
    }

    // P -> bf16 -> wave-private swizzled LDS (A-fragment relayout)
    unsigned short* Pw = &Ps[w][0];
#pragma unroll
    for (int j = 0; j < 4; j++)
#pragma unroll
      for (int r = 0; r < 4; r++) {
        int row = quad * 4 + r;
        int col = j * 16 + r16;
        int chunk = col >> 3;
        Pw[row * KT + ((chunk ^ (row & 7)) * 8 + (col & 7))] = f2bf(p_[j][r]);
      }

    // O += P @ V   (B-frags from vT tile: rows = d, cols = keys)
#pragma unroll
    for (int ks = 0; ks < 2; ks++) {
      bf16x8 pA = *(const bf16x8*)&Pw[r16 * KT + ((ks * 4 + quad) ^ sw) * 8];
      bf16x8 vB[4];
#pragma unroll
      for (int j = 0; j < 4; j++)
        vB[j] = *(const bf16x8*)&Vs[cur][(j * 16 + r16) * KT + ((ks * 4 + quad) ^ sw) * 8];
#pragma unroll
      for (int j = 0; j < 4; j++)
        Oacc[j] = __builtin_amdgcn_mfma_f32_16x16x32_bf16(pA, vB[j], Oacc[j], 0, 0, 0);
    }

    __syncthreads();    // drains prefetch vmcnt; next tile ready
    cur ^= 1;
  }

  // epilogue: O / l -> bf16
#pragma unroll
  for (int r = 0; r < 4; r++) {
    const float inv = 1.0f / lsum[r];
    const long rowg = (long)b_ * SEQ + q0 + w * 16 + quad * 4 + r;
#pragma unroll
    for (int j = 0; j < 4; j++)
      O[rowg * DIM + h_ * DH + j * 16 + r16] = f2bf(Oacc[j][r] * inv);
  }
}

// ---------------------------------------------------------------------------
// LayerNorm: one block (256 thr) per row of 1024 fp32 -> bf16 out
// ---------------------------------------------------------------------------
__global__ void k_layernorm(const float* __restrict__ x, const float* __restrict__ g,
                            const float* __restrict__ b, unsigned short* __restrict__ out)
{
  const int row = blockIdx.x;
  const int t = threadIdx.x;
  float4 v = ((const float4*)(x + (long)row * DIM))[t];
  float s = v.x + v.y + v.z + v.w;
  float q = v.x * v.x + v.y * v.y + v.z * v.z + v.w * v.w;
#pragma unroll
  for (int off = 32; off > 0; off >>= 1) {
    s += __shfl_down(s, off);
    q += __shfl_down(q, off);
  }
  __shared__ float shs[4], shq[4];
  if ((t & 63) == 0) { shs[t >> 6] = s; shq[t >> 6] = q; }
  __syncthreads();
  s = shs[0] + shs[1] + shs[2] + shs[3];
  q = shq[0] + shq[1] + shq[2] + shq[3];
  const float mu  = s * (1.0f / DIM);
  const float var = q * (1.0f / DIM) - mu * mu;
  const float rs  = rsqrtf(var + 1e-5f);
  float4 gg = ((const float4*)g)[t];
  float4 bb = ((const float4*)b)[t];
  ushort4 o;
  o.x = f2bf((v.x - mu) * rs * gg.x + bb.x);
  o.y = f2bf((v.y - mu) * rs * gg.y + bb.y);
  o.z = f2bf((v.z - mu) * rs * gg.z + bb.z);
  o.w = f2bf((v.w - mu) * rs * gg.w + bb.w);
  ((ushort4*)out)[(long)row * (DIM / 4) + t] = o;
}

// ---------------------------------------------------------------------------
// Weight transpose+convert: w[K][N] fp32 -> wT[N][K] bf16. block (64,4), tile 64x64.
// ---------------------------------------------------------------------------
__global__ void k_wtrans(const float* __restrict__ w, unsigned short* __restrict__ wT,
                         int K, int N)
{
  __shared__ unsigned short tile[64][65];
  const int n0 = blockIdx.x * 64, k0 = blockIdx.y * 64;
  const int tx = threadIdx.x, ty = threadIdx.y;
#pragma unroll
  for (int i = 0; i < 16; i++)
    tile[ty + 4 * i][tx] = f2bf(w[(long)(k0 + ty + 4 * i) * N + n0 + tx]);
  __syncthreads();
#pragma unroll
  for (int i = 0; i < 16; i++)
    wT[(long)(n0 + ty + 4 * i) * K + k0 + tx] = tile[tx][ty + 4 * i];
}

// ---------------------------------------------------------------------------
// V transpose: qkv[b, n, 2*DIM + h*64 + d] (bf16) -> vT[(b*16+h)][d][n]
// ---------------------------------------------------------------------------
__global__ void k_vtrans(const unsigned short* __restrict__ qkv, unsigned short* __restrict__ vT)
{
  __shared__ unsigned short tile[64][65];
  const int z = blockIdx.z;
  const int b_ = z >> 4, h_ = z & 15;
  const int n0 = blockIdx.x * 64;
  const int tx = threadIdx.x, ty = threadIdx.y;
  const unsigned short* src = qkv + (long)b_ * SEQ * (3 * DIM) + 2 * DIM + h_ * DH;
#pragma unroll
  for (int i = 0; i < 16; i++)
    tile[ty + 4 * i][tx] = src[(long)(n0 + ty + 4 * i) * (3 * DIM) + tx];
  __syncthreads();
  unsigned short* dst = vT + (long)z * DH * SEQ;
#pragma unroll
  for (int i = 0; i < 16; i++)
    dst[(long)(ty + 4 * i) * SEQ + n0 + tx] = tile[tx][ty + 4 * i];
}

// ---------------------------------------------------------------------------
extern "C" void kernel_launch(void* const* d_in, const int* in_sizes, int n_in,
                              void* d_out, int out_size, void* d_ws, size_t ws_size,
                              hipStream_t stream)
{
  const float* x0   = (const float*)d_in[0];
  const float* rpb  = (const float*)d_in[1];
  const float* ln1g = (const float*)d_in[2];
  const float* ln1b = (const float*)d_in[3];
  const float* wqkv = (const float*)d_in[4];
  const float* wout = (const float*)d_in[5];
  const float* bout = (const float*)d_in[6];
  const float* ln2g = (const float*)d_in[7];
  const float* ln2b = (const float*)d_in[8];
  const float* w1   = (const float*)d_in[9];
  const float* b1   = (const float*)d_in[10];
  const float* w2   = (const float*)d_in[11];
  const float* b2   = (const float*)d_in[12];
  float* x = (float*)d_out;   // running residual stream (fp32), doubles as output

  // workspace layout
  char* p = (char*)d_ws;
  auto alloc = [&](size_t n) { char* r = p; p += (n + 255) & ~(size_t)255; return r; };
  unsigned short* wTqkv = (unsigned short*)alloc((size_t)3 * DIM * DIM * 2);
  unsigned short* wTout = (unsigned short*)alloc((size_t)DIM * DIM * 2);
  unsigned short* wT1   = (unsigned short*)alloc((size_t)FF * DIM * 2);
  unsigned short* wT2   = (unsigned short*)alloc((size_t)DIM * FF * 2);
  unsigned short* hbuf  = (unsigned short*)alloc((size_t)ROWS * DIM * 2);
  unsigned short* qkvb  = (unsigned short*)alloc((size_t)ROWS * 3 * DIM * 2);
  unsigned short* vTb   = (unsigned short*)alloc((size_t)BATCH * HEADS * DH * SEQ * 2);
  unsigned short* obuf  = (unsigned short*)alloc((size_t)ROWS * DIM * 2);
  unsigned short* ffnb  = (unsigned short*)alloc((size_t)ROWS * FF * 2);

  hipMemcpyAsync(x, x0, (size_t)ROWS * DIM * 4, hipMemcpyDeviceToDevice, stream);

  const dim3 tb(64, 4);
  for (int l = 0; l < DEPTH; l++) {
    const float* Wqkv = wqkv + (size_t)l * DIM * 3 * DIM;
    const float* Wout = wout + (size_t)l * DIM * DIM;
    const float* W1   = w1   + (size_t)l * DIM * FF;
    const float* W2   = w2   + (size_t)l * FF * DIM;

    k_wtrans<<<dim3(3 * DIM / 64, DIM / 64), tb, 0, stream>>>(Wqkv, wTqkv, DIM, 3 * DIM);
    k_wtrans<<<dim3(DIM / 64, DIM / 64),     tb, 0, stream>>>(Wout, wTout, DIM, DIM);
    k_wtrans<<<dim3(FF / 64, DIM / 64),      tb, 0, stream>>>(W1,   wT1,   DIM, FF);
    k_wtrans<<<dim3(DIM / 64, FF / 64),      tb, 0, stream>>>(W2,   wT2,   FF, DIM);

    // ---- attention ----
    k_layernorm<<<ROWS, 256, 0, stream>>>(x, ln1g + l * DIM, ln1b + l * DIM, hbuf);

    // qkv: 64x128 tiles (dbuf, 48KB LDS) -> 768 blocks
    gemm_kernel<64, 128, 0, 2, 4><<<dim3(ROWS / 64, 3 * DIM / 128), 256, 0, stream>>>(
        hbuf, DIM, wTqkv, DIM, qkvb, nullptr, 3 * DIM, nullptr, 1.0f, DIM);

    k_vtrans<<<dim3(SEQ / 64, 1, BATCH * HEADS), tb, 0, stream>>>(qkvb, vTb);

    // fused scores+bias+softmax+PV -> obuf   (512 blocks)
    k_flashattn<<<dim3(SEQ / 64, 1, BATCH * HEADS), 256, 0, stream>>>(
        qkvb, vTb, rpb, obuf);

    // x += o @ w_out + b_out : 64x64 (dbuf) -> 512 blocks
    gemm_kernel<64, 64, 2, 2, 4><<<dim3(ROWS / 64, DIM / 64), 256, 0, stream>>>(
        obuf, DIM, wTout, DIM, nullptr, x, DIM, bout + l * DIM, 1.0f, DIM);

    // ---- FFN ----
    k_layernorm<<<ROWS, 256, 0, stream>>>(x, ln2g + l * DIM, ln2b + l * DIM, hbuf);

    // FFN1: 128x128 (dbuf, 64KB LDS) -> 512 blocks
    gemm_kernel<128, 128, 3, 2, 2><<<dim3(ROWS / 128, FF / 128), 256, 0, stream>>>(
        hbuf, DIM, wT1, DIM, ffnb, nullptr, FF, b1 + l * FF, 1.0f, DIM);

    // FFN2: 64x64 (dbuf) -> 512 blocks
    gemm_kernel<64, 64, 2, 2, 4><<<dim3(ROWS / 64, DIM / 64), 256, 0, stream>>>(
        ffnb, FF, wT2, FF, nullptr, x, DIM, b2 + l * DIM, 1.0f, FF);
  }
}

// Round 3
// 1345.757 us; speedup vs baseline: 1.1736x; 1.0102x over previous
//
#include <hip/hip_runtime.h>
#include <stdint.h>

#define DIM   1024
#define DEPTH 6
#define HEADS 16
#define FF    4096
#define SEQ   1024
#define BATCH 2
#define ROWS  (BATCH*SEQ)   // 2048
#define DH    64            // head dim

typedef __bf16 bf16x8 __attribute__((ext_vector_type(8)));
typedef float  f32x4  __attribute__((ext_vector_type(4)));

__device__ __forceinline__ unsigned short f2bf(float f) {
  unsigned int u = __builtin_bit_cast(unsigned int, f);
  u += 0x7fff + ((u >> 16) & 1);          // round-to-nearest-even
  return (unsigned short)(u >> 16);
}
__device__ __forceinline__ float bf2f(unsigned short h) {
  unsigned int u = ((unsigned int)h) << 16;
  return __builtin_bit_cast(float, u);
}

// async global->LDS, 16 bytes per lane. LDS dest must be uniform-base + lane*16.
__device__ __forceinline__ void async_load16(const void* g, void* l) {
  __builtin_amdgcn_global_load_lds(
      (const __attribute__((address_space(1))) unsigned int*)g,
      (__attribute__((address_space(3))) unsigned int*)l, 16, 0, 0);
}

// ---------------------------------------------------------------------------
// GEMM: C[M,N] = A[M,K] @ B^T  where B is stored [N][K] (bf16, K contiguous).
// BK=64, 256 threads (4 waves). 16x16x32 bf16 MFMA.
// LDS tiles XOR-swizzled: 16B chunk c of row r lives at chunk (c ^ (r&7)).
// NBUF=2: double-buffered LDS; prefetch of tile t+1 issued BEFORE compute of
//   tile t; the single __syncthreads() (with its implicit vmcnt(0) drain) sits
//   AFTER compute -> load latency hides under MFMA.
// EPI: 0 = store bf16
//      2 = Cf[m][n] += acc + bias1[n]                         (residual adds)
//      3 = store bf16 of gelu(acc + bias1[n])                 (FFN mid)
// ---------------------------------------------------------------------------
template<int BM, int BN, int EPI, int NBUF, int MINW>
__global__ void __launch_bounds__(256, MINW)
gemm_kernel(const unsigned short* __restrict__ A, long lda,
            const unsigned short* __restrict__ B, long ldb,
            unsigned short* __restrict__ Cb, float* __restrict__ Cf, long ldc,
            const float* __restrict__ bias1, float scale, int K)
{
  constexpr int BK = 64;                    // 8 chunks of 16B per row
  __shared__ unsigned short As[NBUF * BM * BK];
  __shared__ unsigned short Bs[NBUF * BN * BK];

  const int tid  = threadIdx.x;
  const int row0 = blockIdx.x * BM;
  const int col0 = blockIdx.y * BN;

  constexpr int WGN = 2;                    // waves along N
  constexpr int WGM = 2;                    // waves along M
  constexpr int WTM = BM / WGM;             // wave tile M
  constexpr int WTN = BN / WGN;             // wave tile N
  constexpr int ITM = WTM / 16;
  constexpr int ITN = WTN / 16;

  const int w = tid >> 6, l = tid & 63;
  const int quad = l >> 4, r16 = l & 15;
  const int wm = (w / WGN) * WTM;
  const int wn = (w % WGN) * WTN;
  const int sw = r16 & 7;                   // read-side XOR swizzle key

  f32x4 acc[ITM][ITN] = {};

  constexpr int APASS = (BM * 8) / 256;     // 16B chunks per thread for A tile
  constexpr int BPASS = (BN * 8) / 256;

  const unsigned short* Ag = A + (long)row0 * lda;
  const unsigned short* Bg = B + (long)col0 * ldb;

  auto stage = [&](int buf, long k0) {
    unsigned short* Asb = &As[buf * (BM * BK)];
    unsigned short* Bsb = &Bs[buf * (BN * BK)];
#pragma unroll
    for (int p = 0; p < APASS; p++) {
      int flat = p * 256 + tid;
      int r = flat >> 3, cl = flat & 7;
      int cg = cl ^ (r & 7);                // fetch the chunk that belongs at slot cl
      async_load16(Ag + (long)r * lda + k0 + cg * 8, &Asb[flat * 8]);
    }
#pragma unroll
    for (int p = 0; p < BPASS; p++) {
      int flat = p * 256 + tid;
      int r = flat >> 3, cl = flat & 7;
      int cg = cl ^ (r & 7);
      async_load16(Bg + (long)r * ldb + k0 + cg * 8, &Bsb[flat * 8]);
    }
  };

  auto compute = [&](int buf) {
    const unsigned short* Asb = &As[buf * (BM * BK)];
    const unsigned short* Bsb = &Bs[buf * (BN * BK)];
#pragma unroll
    for (int ks = 0; ks < 2; ks++) {
      const int c = ks * 4 + quad;          // logical 16B chunk index
      bf16x8 af[ITM], bfr[ITN];
#pragma unroll
      for (int i = 0; i < ITM; i++)
        af[i] = *(const bf16x8*)&Asb[(wm + i * 16 + r16) * BK + (c ^ sw) * 8];
#pragma unroll
      for (int j = 0; j < ITN; j++)
        bfr[j] = *(const bf16x8*)&Bsb[(wn + j * 16 + r16) * BK + (c ^ sw) * 8];
#pragma unroll
      for (int i = 0; i < ITM; i++)
#pragma unroll
        for (int j = 0; j < ITN; j++)
          acc[i][j] = __builtin_amdgcn_mfma_f32_16x16x32_bf16(af[i], bfr[j], acc[i][j], 0, 0, 0);
    }
  };

  if constexpr (NBUF == 1) {
    stage(0, 0);
    __syncthreads();
    compute(0);
  } else {
    stage(0, 0);
    __syncthreads();
    int cur = 0;
    for (long k0 = BK; k0 < K; k0 += BK) {
      stage(cur ^ 1, k0);                   // issue next-tile loads (async)
      compute(cur);                         // MFMA on current tile
      __syncthreads();                      // vmcnt(0)+barrier: next tile ready
      cur ^= 1;
    }
    compute(cur);                           // last tile, no prefetch
  }

  // epilogue: C/D layout row = quad*4 + reg, col = lane&15
#pragma unroll
  for (int i = 0; i < ITM; i++) {
#pragma unroll
    for (int j = 0; j < ITN; j++) {
      const int rr = row0 + wm + i * 16 + quad * 4;
      const int cc = col0 + wn + j * 16 + r16;
#pragma unroll
      for (int r = 0; r < 4; r++) {
        const long idx = (long)(rr + r) * ldc + cc;
        float v = acc[i][j][r];
        if constexpr (EPI == 0) {
          Cb[idx] = f2bf(v);
        } else if constexpr (EPI == 2) {
          Cf[idx] += v + bias1[cc];
        } else if constexpr (EPI == 3) {
          v += bias1[cc];
          float gl = 0.5f * v * (1.0f + erff(v * 0.70710678118654752f));
          Cb[idx] = f2bf(gl);
        }
      }
    }
  }
}

// ---------------------------------------------------------------------------
// Fused flash attention (log2-domain softmax, defer-max rescale).
// Grid: (SEQ/64, 1, BATCH*HEADS), 256 threads (4 waves).
// Per block: 64 Q-rows of one (b,h). Wave w owns Q rows [w*16, w*16+16).
// rpbh is rpb pre-converted to bf16 and pre-scaled by log2(e); scores are kept
// in log2 domain so P = exp2(sc - m) maps to a single v_exp_f32.
// ---------------------------------------------------------------------------
__global__ void __launch_bounds__(256, 2)
k_flashattn(const unsigned short* __restrict__ qkv,  // [b][n][3*DIM]
            const unsigned short* __restrict__ vT,   // [b*16+h][d][n]
            const unsigned short* __restrict__ rpbh, // [h][n][n] bf16, *log2e
            unsigned short* __restrict__ O)          // [b][n][DIM]
{
  constexpr int QT = 64;          // q rows per block
  constexpr int KT = 64;          // keys per tile
  constexpr int NT = SEQ / KT;    // 16 tiles
  constexpr float SCL2 = 0.18033688f;   // 0.125 * log2(e)
  constexpr float THR  = 11.5415603f;   // 8 * log2(e)

  __shared__ __align__(16) unsigned short Qs[QT * DH];       // 8 KB
  __shared__ __align__(16) unsigned short Ks[2][KT * DH];    // 16 KB
  __shared__ __align__(16) unsigned short Vs[2][DH * KT];    // 16 KB
  __shared__ __align__(16) unsigned short Ps[4][16 * KT];    // 8 KB (per-wave)

  const int z = blockIdx.z;
  const int b_ = z >> 4, h_ = z & 15;
  const int q0 = blockIdx.x * QT;
  const int tid = threadIdx.x;
  const int w = tid >> 6, l = tid & 63;
  const int quad = l >> 4, r16 = l & 15;
  const int sw = r16 & 7;

  const unsigned short* Qg = qkv + (long)b_ * SEQ * (3 * DIM) + h_ * DH;
  const unsigned short* Kg = Qg + DIM;
  const unsigned short* Vg = vT + (long)z * DH * SEQ;
  const unsigned short* Rg = rpbh + (long)h_ * SEQ * SEQ + (long)q0 * SEQ;

  auto stageKV = [&](int buf, int kt) {
#pragma unroll
    for (int p = 0; p < 2; p++) {
      int flat = p * 256 + tid;
      int r = flat >> 3, cl = flat & 7, cg = cl ^ (r & 7);
      async_load16(Kg + (long)(kt * KT + r) * (3 * DIM) + cg * 8, &Ks[buf][flat * 8]);
    }
#pragma unroll
    for (int p = 0; p < 2; p++) {
      int flat = p * 256 + tid;
      int r = flat >> 3, cl = flat & 7, cg = cl ^ (r & 7);
      async_load16(Vg + (long)r * SEQ + kt * KT + cg * 8, &Vs[buf][flat * 8]);
    }
  };

  // stage Q + first K/V
#pragma unroll
  for (int p = 0; p < 2; p++) {
    int flat = p * 256 + tid;
    int r = flat >> 3, cl = flat & 7, cg = cl ^ (r & 7);
    async_load16(Qg + (long)(q0 + r) * (3 * DIM) + cg * 8, &Qs[flat * 8]);
  }
  stageKV(0, 0);
  __syncthreads();

  // Q fragments (held in registers for the whole kernel)
  bf16x8 qA[2];
#pragma unroll
  for (int ks = 0; ks < 2; ks++)
    qA[ks] = *(const bf16x8*)&Qs[(w * 16 + r16) * DH + (((ks * 4 + quad)) ^ sw) * 8];

  f32x4 Oacc[4] = {};
  float m[4], lsum[4];
#pragma unroll
  for (int r = 0; r < 4; r++) { m[r] = -1e30f; lsum[r] = 0.0f; }

  int cur = 0;
  for (int kt = 0; kt < NT; kt++) {
    if (kt + 1 < NT) stageKV(cur ^ 1, kt + 1);   // async prefetch next tile

    // rpb bias loads (bf16, log2-scaled) — issued before MFMAs so they overlap
    float bias[4][4];
    const unsigned short* Rt = Rg + kt * KT;
#pragma unroll
    for (int j = 0; j < 4; j++)
#pragma unroll
      for (int r = 0; r < 4; r++)
        bias[j][r] = bf2f(Rt[(long)(w * 16 + quad * 4 + r) * SEQ + j * 16 + r16]);

    // S = Q @ K^T  (rows = q, cols = keys of this tile)
    f32x4 s[4] = {};
#pragma unroll
    for (int ks = 0; ks < 2; ks++) {
      bf16x8 kB[4];
#pragma unroll
      for (int j = 0; j < 4; j++)
        kB[j] = *(const bf16x8*)&Ks[cur][(j * 16 + r16) * DH + ((ks * 4 + quad) ^ sw) * 8];
#pragma unroll
      for (int j = 0; j < 4; j++)
        s[j] = __builtin_amdgcn_mfma_f32_16x16x32_bf16(qA[ks], kB[j], s[j], 0, 0, 0);
    }

    // scores (log2 domain) + online softmax with defer-max.
    float sc[4][4], p_[4][4], mt[4], ts[4];
#pragma unroll
    for (int j = 0; j < 4; j++)
#pragma unroll
      for (int r = 0; r < 4; r++)
        sc[j][r] = __builtin_fmaf(s[j][r], SCL2, bias[j][r]);
#pragma unroll
    for (int r = 0; r < 4; r++) {
      mt[r] = fmaxf(fmaxf(sc[0][r], sc[1][r]), fmaxf(sc[2][r], sc[3][r]));
#pragma unroll
      for (int msk = 1; msk < 16; msk <<= 1)
        mt[r] = fmaxf(mt[r], __shfl_xor(mt[r], msk));
      // defer-max: only rescale when tile max exceeds running max by > THR
      if (mt[r] > m[r] + THR) {
        const float rs = __builtin_amdgcn_exp2f(m[r] - mt[r]);
        m[r] = mt[r];
#pragma unroll
        for (int j = 0; j < 4; j++) Oacc[j][r] *= rs;
        lsum[r] *= rs;
      }
#pragma unroll
      for (int j = 0; j < 4; j++)
        p_[j][r] = __builtin_amdgcn_exp2f(sc[j][r] - m[r]);
      ts[r] = p_[0][r] + p_[1][r] + p_[2][r] + p_[3][r];
#pragma unroll
      for (int msk = 1; msk < 16; msk <<= 1)
        ts[r] += __shfl_xor(ts[r], msk);
      lsum[r] += ts[r];
    }

    // P -> bf16 -> wave-private swizzled LDS (A-fragment relayout)
    unsigned short* Pw = &Ps[w][0];
#pragma unroll
    for (int j = 0; j < 4; j++)
#pragma unroll
      for (int r = 0; r < 4; r++) {
        int row = quad * 4 + r;
        int col = j * 16 + r16;
        int chunk = col >> 3;
        Pw[row * KT + ((chunk ^ (row & 7)) * 8 + (col & 7))] = f2bf(p_[j][r]);
      }

    // O += P @ V   (B-frags from vT tile: rows = d, cols = keys)
#pragma unroll
    for (int ks = 0; ks < 2; ks++) {
      bf16x8 pA = *(const bf16x8*)&Pw[r16 * KT + ((ks * 4 + quad) ^ sw) * 8];
      bf16x8 vB[4];
#pragma unroll
      for (int j = 0; j < 4; j++)
        vB[j] = *(const bf16x8*)&Vs[cur][(j * 16 + r16) * KT + ((ks * 4 + quad) ^ sw) * 8];
#pragma unroll
      for (int j = 0; j < 4; j++)
        Oacc[j] = __builtin_amdgcn_mfma_f32_16x16x32_bf16(pA, vB[j], Oacc[j], 0, 0, 0);
    }

    __syncthreads();    // drains prefetch vmcnt; next tile ready
    cur ^= 1;
  }

  // epilogue: O / l -> bf16
#pragma unroll
  for (int r = 0; r < 4; r++) {
    const float inv = 1.0f / lsum[r];
    const long rowg = (long)b_ * SEQ + q0 + w * 16 + quad * 4 + r;
#pragma unroll
    for (int j = 0; j < 4; j++)
      O[rowg * DIM + h_ * DH + j * 16 + r16] = f2bf(Oacc[j][r] * inv);
  }
}

// ---------------------------------------------------------------------------
// LayerNorm: one block (256 thr) per row of 1024 fp32 -> bf16 out
// ---------------------------------------------------------------------------
__global__ void k_layernorm(const float* __restrict__ x, const float* __restrict__ g,
                            const float* __restrict__ b, unsigned short* __restrict__ out)
{
  const int row = blockIdx.x;
  const int t = threadIdx.x;
  float4 v = ((const float4*)(x + (long)row * DIM))[t];
  float s = v.x + v.y + v.z + v.w;
  float q = v.x * v.x + v.y * v.y + v.z * v.z + v.w * v.w;
#pragma unroll
  for (int off = 32; off > 0; off >>= 1) {
    s += __shfl_down(s, off);
    q += __shfl_down(q, off);
  }
  __shared__ float shs[4], shq[4];
  if ((t & 63) == 0) { shs[t >> 6] = s; shq[t >> 6] = q; }
  __syncthreads();
  s = shs[0] + shs[1] + shs[2] + shs[3];
  q = shq[0] + shq[1] + shq[2] + shq[3];
  const float mu  = s * (1.0f / DIM);
  const float var = q * (1.0f / DIM) - mu * mu;
  const float rs  = rsqrtf(var + 1e-5f);
  float4 gg = ((const float4*)g)[t];
  float4 bb = ((const float4*)b)[t];
  ushort4 o;
  o.x = f2bf((v.x - mu) * rs * gg.x + bb.x);
  o.y = f2bf((v.y - mu) * rs * gg.y + bb.y);
  o.z = f2bf((v.z - mu) * rs * gg.z + bb.z);
  o.w = f2bf((v.w - mu) * rs * gg.w + bb.w);
  ((ushort4*)out)[(long)row * (DIM / 4) + t] = o;
}

// ---------------------------------------------------------------------------
// rpb fp32 -> bf16, pre-scaled by log2(e). 16384 blocks x 256 thr x 1 float4.
// ---------------------------------------------------------------------------
__global__ void k_cvtrpb(const float* __restrict__ src, unsigned short* __restrict__ dst)
{
  const long i = ((long)blockIdx.x * 256 + threadIdx.x) * 4;
  float4 v = *(const float4*)(src + i);
  ushort4 o;
  o.x = f2bf(v.x * 1.44269504f);
  o.y = f2bf(v.y * 1.44269504f);
  o.z = f2bf(v.z * 1.44269504f);
  o.w = f2bf(v.w * 1.44269504f);
  *(ushort4*)(dst + i) = o;
}

// ---------------------------------------------------------------------------
// Fused weight transpose+convert for all 4 weights of one layer.
// w[K][N] fp32 -> wT[N][K] bf16, 64x64 tiles, block (64,4).
// Flat tile id decodes which weight: [0,768) wqkv, [768,1024) wout,
// [1024,2048) w1, [2048,3072) w2.
// ---------------------------------------------------------------------------
__global__ void k_wtrans_all(const float* __restrict__ wqkv, const float* __restrict__ wout,
                             const float* __restrict__ w1,   const float* __restrict__ w2,
                             unsigned short* __restrict__ wTqkv, unsigned short* __restrict__ wTout,
                             unsigned short* __restrict__ wT1,   unsigned short* __restrict__ wT2)
{
  __shared__ unsigned short tile[64][65];
  int t = blockIdx.x;
  const float* w; unsigned short* wT; int K, N;
  if (t < 768)        {            w = wqkv; wT = wTqkv; K = DIM; N = 3 * DIM; }
  else if (t < 1024)  { t -= 768;  w = wout; wT = wTout; K = DIM; N = DIM; }
  else if (t < 2048)  { t -= 1024; w = w1;   wT = wT1;   K = DIM; N = FF; }
  else                { t -= 2048; w = w2;   wT = wT2;   K = FF;  N = DIM; }
  const int nt = N / 64;
  const int n0 = (t % nt) * 64, k0 = (t / nt) * 64;
  const int tx = threadIdx.x, ty = threadIdx.y;
#pragma unroll
  for (int i = 0; i < 16; i++)
    tile[ty + 4 * i][tx] = f2bf(w[(long)(k0 + ty + 4 * i) * N + n0 + tx]);
  __syncthreads();
#pragma unroll
  for (int i = 0; i < 16; i++)
    wT[(long)(n0 + ty + 4 * i) * K + k0 + tx] = tile[tx][ty + 4 * i];
}

// ---------------------------------------------------------------------------
// V transpose: qkv[b, n, 2*DIM + h*64 + d] (bf16) -> vT[(b*16+h)][d][n]
// ---------------------------------------------------------------------------
__global__ void k_vtrans(const unsigned short* __restrict__ qkv, unsigned short* __restrict__ vT)
{
  __shared__ unsigned short tile[64][65];
  const int z = blockIdx.z;
  const int b_ = z >> 4, h_ = z & 15;
  const int n0 = blockIdx.x * 64;
  const int tx = threadIdx.x, ty = threadIdx.y;
  const unsigned short* src = qkv + (long)b_ * SEQ * (3 * DIM) + 2 * DIM + h_ * DH;
#pragma unroll
  for (int i = 0; i < 16; i++)
    tile[ty + 4 * i][tx] = src[(long)(n0 + ty + 4 * i) * (3 * DIM) + tx];
  __syncthreads();
  unsigned short* dst = vT + (long)z * DH * SEQ;
#pragma unroll
  for (int i = 0; i < 16; i++)
    dst[(long)(ty + 4 * i) * SEQ + n0 + tx] = tile[tx][ty + 4 * i];
}

// ---------------------------------------------------------------------------
extern "C" void kernel_launch(void* const* d_in, const int* in_sizes, int n_in,
                              void* d_out, int out_size, void* d_ws, size_t ws_size,
                              hipStream_t stream)
{
  const float* x0   = (const float*)d_in[0];
  const float* rpb  = (const float*)d_in[1];
  const float* ln1g = (const float*)d_in[2];
  const float* ln1b = (const float*)d_in[3];
  const float* wqkv = (const float*)d_in[4];
  const float* wout = (const float*)d_in[5];
  const float* bout = (const float*)d_in[6];
  const float* ln2g = (const float*)d_in[7];
  const float* ln2b = (const float*)d_in[8];
  const float* w1   = (const float*)d_in[9];
  const float* b1   = (const float*)d_in[10];
  const float* w2   = (const float*)d_in[11];
  const float* b2   = (const float*)d_in[12];
  float* x = (float*)d_out;   // running residual stream (fp32), doubles as output

  // workspace layout (~100 MB)
  char* p = (char*)d_ws;
  auto alloc = [&](size_t n) { char* r = p; p += (n + 255) & ~(size_t)255; return r; };
  unsigned short* wTqkv = (unsigned short*)alloc((size_t)3 * DIM * DIM * 2);
  unsigned short* wTout = (unsigned short*)alloc((size_t)DIM * DIM * 2);
  unsigned short* wT1   = (unsigned short*)alloc((size_t)FF * DIM * 2);
  unsigned short* wT2   = (unsigned short*)alloc((size_t)DIM * FF * 2);
  unsigned short* hbuf  = (unsigned short*)alloc((size_t)ROWS * DIM * 2);
  unsigned short* qkvb  = (unsigned short*)alloc((size_t)ROWS * 3 * DIM * 2);
  unsigned short* vTb   = (unsigned short*)alloc((size_t)BATCH * HEADS * DH * SEQ * 2);
  unsigned short* obuf  = (unsigned short*)alloc((size_t)ROWS * DIM * 2);
  unsigned short* ffnb  = (unsigned short*)alloc((size_t)ROWS * FF * 2);
  unsigned short* rpbh  = (unsigned short*)alloc((size_t)HEADS * SEQ * SEQ * 2);

  hipMemcpyAsync(x, x0, (size_t)ROWS * DIM * 4, hipMemcpyDeviceToDevice, stream);

  // one-time: rpb fp32 -> bf16 * log2e   (16 * 1024 * 1024 / 4 / 256 = 16384 blocks)
  k_cvtrpb<<<dim3(16384), 256, 0, stream>>>(rpb, rpbh);

  const dim3 tb(64, 4);
  for (int l = 0; l < DEPTH; l++) {
    const float* Wqkv = wqkv + (size_t)l * DIM * 3 * DIM;
    const float* Wout = wout + (size_t)l * DIM * DIM;
    const float* W1   = w1   + (size_t)l * DIM * FF;
    const float* W2   = w2   + (size_t)l * FF * DIM;

    // all 4 weight transposes in one launch (3072 tiles)
    k_wtrans_all<<<dim3(3072), tb, 0, stream>>>(Wqkv, Wout, W1, W2,
                                                wTqkv, wTout, wT1, wT2);

    // ---- attention ----
    k_layernorm<<<ROWS, 256, 0, stream>>>(x, ln1g + l * DIM, ln1b + l * DIM, hbuf);

    // qkv: 64x128 tiles (dbuf, 48KB LDS) -> 768 blocks
    gemm_kernel<64, 128, 0, 2, 4><<<dim3(ROWS / 64, 3 * DIM / 128), 256, 0, stream>>>(
        hbuf, DIM, wTqkv, DIM, qkvb, nullptr, 3 * DIM, nullptr, 1.0f, DIM);

    k_vtrans<<<dim3(SEQ / 64, 1, BATCH * HEADS), tb, 0, stream>>>(qkvb, vTb);

    // fused scores+bias+softmax+PV -> obuf   (512 blocks)
    k_flashattn<<<dim3(SEQ / 64, 1, BATCH * HEADS), 256, 0, stream>>>(
        qkvb, vTb, rpbh, obuf);

    // x += o @ w_out + b_out : 64x64 (dbuf) -> 512 blocks
    gemm_kernel<64, 64, 2, 2, 4><<<dim3(ROWS / 64, DIM / 64), 256, 0, stream>>>(
        obuf, DIM, wTout, DIM, nullptr, x, DIM, bout + l * DIM, 1.0f, DIM);

    // ---- FFN ----
    k_layernorm<<<ROWS, 256, 0, stream>>>(x, ln2g + l * DIM, ln2b + l * DIM, hbuf);

    // FFN1: 128x128 (dbuf, 64KB LDS) -> 512 blocks
    gemm_kernel<128, 128, 3, 2, 2><<<dim3(ROWS / 128, FF / 128), 256, 0, stream>>>(
        hbuf, DIM, wT1, DIM, ffnb, nullptr, FF, b1 + l * FF, 1.0f, DIM);

    // FFN2: 64x64 (dbuf) -> 512 blocks
    gemm_kernel<64, 64, 2, 2, 4><<<dim3(ROWS / 64, DIM / 64), 256, 0, stream>>>(
        ffnb, FF, wT2, FF, nullptr, x, DIM, b2 + l * DIM, 1.0f, FF);
  }
}

// Round 4
// 1277.710 us; speedup vs baseline: 1.2361x; 1.0533x over previous
//
#include <hip/hip_runtime.h>
#include <stdint.h>

#define DIM   1024
#define DEPTH 6
#define HEADS 16
#define FF    4096
#define SEQ   1024
#define BATCH 2
#define ROWS  (BATCH*SEQ)   // 2048
#define DH    64            // head dim

typedef __bf16 bf16x8 __attribute__((ext_vector_type(8)));
typedef float  f32x4  __attribute__((ext_vector_type(4)));

__device__ __forceinline__ unsigned short f2bf(float f) {
  unsigned int u = __builtin_bit_cast(unsigned int, f);
  u += 0x7fff + ((u >> 16) & 1);          // round-to-nearest-even
  return (unsigned short)(u >> 16);
}
__device__ __forceinline__ float bf2f(unsigned short h) {
  unsigned int u = ((unsigned int)h) << 16;
  return __builtin_bit_cast(float, u);
}

// async global->LDS, 16 bytes per lane. LDS dest must be uniform-base + lane*16.
__device__ __forceinline__ void async_load16(const void* g, void* l) {
  __builtin_amdgcn_global_load_lds(
      (const __attribute__((address_space(1))) unsigned int*)g,
      (__attribute__((address_space(3))) unsigned int*)l, 16, 0, 0);
}

// ---------------------------------------------------------------------------
// GEMM: C[M,N] = A[M,K] @ B^T  where B is stored [N][K] (bf16, K contiguous).
// BK=64, 256 threads (4 waves). 16x16x32 bf16 MFMA.
// LDS tiles XOR-swizzled: 16B chunk c of row r lives at chunk (c ^ (r&7)).
//
// Structure: single-buffered, 2 barriers per K-step (stage -> sync -> compute
// -> sync). This is latency-bound per-step, so throughput comes from TLP:
// 64x64 tiles (16 KB LDS) allow up to 8-10 blocks/CU; grids are sized/split
// so every GEMM gets >= 4 blocks/CU.
//
// SPLITK>1: blockIdx.z = K-split index; EPI==4 stores fp32 partials to
// Cf[z*pstride + idx] (plain streaming stores; a separate reduce kernel sums).
//
// EPI: 0 = store bf16
//      3 = store bf16 of gelu(acc + bias1[n])                 (FFN mid)
//      4 = store fp32 partial (split-K)
// ---------------------------------------------------------------------------
template<int BM, int BN, int EPI, int SPLITK, int MINW>
__global__ void __launch_bounds__(256, MINW)
gemm_kernel(const unsigned short* __restrict__ A, long lda,
            const unsigned short* __restrict__ B, long ldb,
            unsigned short* __restrict__ Cb, float* __restrict__ Cf, long ldc,
            const float* __restrict__ bias1, int K, long pstride)
{
  constexpr int BK = 64;                    // 8 chunks of 16B per row
  const int z = blockIdx.z;
  const int Kloc = K / SPLITK;
  const long kbase = (long)z * Kloc;

  __shared__ unsigned short As[BM * BK];
  __shared__ unsigned short Bs[BN * BK];

  const int tid  = threadIdx.x;
  const int row0 = blockIdx.x * BM;
  const int col0 = blockIdx.y * BN;

  constexpr int WGN = 2;                    // waves along N
  constexpr int WGM = 2;                    // waves along M
  constexpr int WTM = BM / WGM;             // wave tile M
  constexpr int WTN = BN / WGN;             // wave tile N
  constexpr int ITM = WTM / 16;
  constexpr int ITN = WTN / 16;

  const int w = tid >> 6, l = tid & 63;
  const int quad = l >> 4, r16 = l & 15;
  const int wm = (w / WGN) * WTM;
  const int wn = (w % WGN) * WTN;
  const int sw = r16 & 7;                   // read-side XOR swizzle key

  f32x4 acc[ITM][ITN] = {};

  constexpr int APASS = (BM * 8) / 256;     // 16B chunks per thread for A tile
  constexpr int BPASS = (BN * 8) / 256;

  const unsigned short* Ag = A + (long)row0 * lda;
  const unsigned short* Bg = B + (long)col0 * ldb;

  for (long k0 = kbase; k0 < kbase + Kloc; k0 += BK) {
#pragma unroll
    for (int p = 0; p < APASS; p++) {
      int flat = p * 256 + tid;
      int r = flat >> 3, cl = flat & 7;
      int cg = cl ^ (r & 7);                // fetch the chunk that belongs at slot cl
      async_load16(Ag + (long)r * lda + k0 + cg * 8, &As[flat * 8]);
    }
#pragma unroll
    for (int p = 0; p < BPASS; p++) {
      int flat = p * 256 + tid;
      int r = flat >> 3, cl = flat & 7;
      int cg = cl ^ (r & 7);
      async_load16(Bg + (long)r * ldb + k0 + cg * 8, &Bs[flat * 8]);
    }
    __syncthreads();   // drains vmcnt: LDS now holds the tiles
#pragma unroll
    for (int ks = 0; ks < 2; ks++) {
      const int c = ks * 4 + quad;          // logical 16B chunk index
      bf16x8 af[ITM], bfr[ITN];
#pragma unroll
      for (int i = 0; i < ITM; i++)
        af[i] = *(const bf16x8*)&As[(wm + i * 16 + r16) * BK + (c ^ sw) * 8];
#pragma unroll
      for (int j = 0; j < ITN; j++)
        bfr[j] = *(const bf16x8*)&Bs[(wn + j * 16 + r16) * BK + (c ^ sw) * 8];
#pragma unroll
      for (int i = 0; i < ITM; i++)
#pragma unroll
        for (int j = 0; j < ITN; j++)
          acc[i][j] = __builtin_amdgcn_mfma_f32_16x16x32_bf16(af[i], bfr[j], acc[i][j], 0, 0, 0);
    }
    __syncthreads();
  }

  // epilogue: C/D layout row = quad*4 + reg, col = lane&15
#pragma unroll
  for (int i = 0; i < ITM; i++) {
#pragma unroll
    for (int j = 0; j < ITN; j++) {
      const int rr = row0 + wm + i * 16 + quad * 4;
      const int cc = col0 + wn + j * 16 + r16;
#pragma unroll
      for (int r = 0; r < 4; r++) {
        const long idx = (long)(rr + r) * ldc + cc;
        float v = acc[i][j][r];
        if constexpr (EPI == 0) {
          Cb[idx] = f2bf(v);
        } else if constexpr (EPI == 3) {
          v += bias1[cc];
          float gl = 0.5f * v * (1.0f + erff(v * 0.70710678118654752f));
          Cb[idx] = f2bf(gl);
        } else if constexpr (EPI == 4) {
          Cf[(long)z * pstride + idx] = v;
        }
      }
    }
  }
}

// ---------------------------------------------------------------------------
// Split-K reduce: x[i] += pbuf[0][i] + pbuf[1][i] + bias[col].
// float4 per thread; grid = ROWS*DIM/1024 blocks x 256 thr.
// ---------------------------------------------------------------------------
__global__ void k_reduce2(float* __restrict__ x, const float* __restrict__ pbuf,
                          const float* __restrict__ bias)
{
  const long i = (long)blockIdx.x * 256 + threadIdx.x;   // float4 index
  float4 a  = ((float4*)x)[i];
  float4 p0 = ((const float4*)pbuf)[i];
  float4 p1 = ((const float4*)(pbuf + (long)ROWS * DIM))[i];
  float4 bb = ((const float4*)bias)[i & (DIM / 4 - 1)];
  a.x += p0.x + p1.x + bb.x;
  a.y += p0.y + p1.y + bb.y;
  a.z += p0.z + p1.z + bb.z;
  a.w += p0.w + p1.w + bb.w;
  ((float4*)x)[i] = a;
}

// ---------------------------------------------------------------------------
// Fused flash attention (log2-domain softmax, defer-max rescale).
// Grid: (SEQ/64, 1, BATCH*HEADS), 256 threads (4 waves).
// ---------------------------------------------------------------------------
__global__ void __launch_bounds__(256, 2)
k_flashattn(const unsigned short* __restrict__ qkv,  // [b][n][3*DIM]
            const unsigned short* __restrict__ vT,   // [b*16+h][d][n]
            const unsigned short* __restrict__ rpbh, // [h][n][n] bf16, *log2e
            unsigned short* __restrict__ O)          // [b][n][DIM]
{
  constexpr int QT = 64;          // q rows per block
  constexpr int KT = 64;          // keys per tile
  constexpr int NT = SEQ / KT;    // 16 tiles
  constexpr float SCL2 = 0.18033688f;   // 0.125 * log2(e)
  constexpr float THR  = 11.5415603f;   // 8 * log2(e)

  __shared__ __align__(16) unsigned short Qs[QT * DH];       // 8 KB
  __shared__ __align__(16) unsigned short Ks[2][KT * DH];    // 16 KB
  __shared__ __align__(16) unsigned short Vs[2][DH * KT];    // 16 KB
  __shared__ __align__(16) unsigned short Ps[4][16 * KT];    // 8 KB (per-wave)

  const int z = blockIdx.z;
  const int b_ = z >> 4, h_ = z & 15;
  const int q0 = blockIdx.x * QT;
  const int tid = threadIdx.x;
  const int w = tid >> 6, l = tid & 63;
  const int quad = l >> 4, r16 = l & 15;
  const int sw = r16 & 7;

  const unsigned short* Qg = qkv + (long)b_ * SEQ * (3 * DIM) + h_ * DH;
  const unsigned short* Kg = Qg + DIM;
  const unsigned short* Vg = vT + (long)z * DH * SEQ;
  const unsigned short* Rg = rpbh + (long)h_ * SEQ * SEQ + (long)q0 * SEQ;

  auto stageKV = [&](int buf, int kt) {
#pragma unroll
    for (int p = 0; p < 2; p++) {
      int flat = p * 256 + tid;
      int r = flat >> 3, cl = flat & 7, cg = cl ^ (r & 7);
      async_load16(Kg + (long)(kt * KT + r) * (3 * DIM) + cg * 8, &Ks[buf][flat * 8]);
    }
#pragma unroll
    for (int p = 0; p < 2; p++) {
      int flat = p * 256 + tid;
      int r = flat >> 3, cl = flat & 7, cg = cl ^ (r & 7);
      async_load16(Vg + (long)r * SEQ + kt * KT + cg * 8, &Vs[buf][flat * 8]);
    }
  };

  // stage Q + first K/V
#pragma unroll
  for (int p = 0; p < 2; p++) {
    int flat = p * 256 + tid;
    int r = flat >> 3, cl = flat & 7, cg = cl ^ (r & 7);
    async_load16(Qg + (long)(q0 + r) * (3 * DIM) + cg * 8, &Qs[flat * 8]);
  }
  stageKV(0, 0);
  __syncthreads();

  // Q fragments (held in registers for the whole kernel)
  bf16x8 qA[2];
#pragma unroll
  for (int ks = 0; ks < 2; ks++)
    qA[ks] = *(const bf16x8*)&Qs[(w * 16 + r16) * DH + (((ks * 4 + quad)) ^ sw) * 8];

  f32x4 Oacc[4] = {};
  float m[4], lsum[4];
#pragma unroll
  for (int r = 0; r < 4; r++) { m[r] = -1e30f; lsum[r] = 0.0f; }

  int cur = 0;
  for (int kt = 0; kt < NT; kt++) {
    if (kt + 1 < NT) stageKV(cur ^ 1, kt + 1);   // async prefetch next tile

    // rpb bias loads (bf16, log2-scaled) — issued before MFMAs so they overlap
    float bias[4][4];
    const unsigned short* Rt = Rg + kt * KT;
#pragma unroll
    for (int j = 0; j < 4; j++)
#pragma unroll
      for (int r = 0; r < 4; r++)
        bias[j][r] = bf2f(Rt[(long)(w * 16 + quad * 4 + r) * SEQ + j * 16 + r16]);

    // S = Q @ K^T  (rows = q, cols = keys of this tile)
    f32x4 s[4] = {};
#pragma unroll
    for (int ks = 0; ks < 2; ks++) {
      bf16x8 kB[4];
#pragma unroll
      for (int j = 0; j < 4; j++)
        kB[j] = *(const bf16x8*)&Ks[cur][(j * 16 + r16) * DH + ((ks * 4 + quad) ^ sw) * 8];
#pragma unroll
      for (int j = 0; j < 4; j++)
        s[j] = __builtin_amdgcn_mfma_f32_16x16x32_bf16(qA[ks], kB[j], s[j], 0, 0, 0);
    }

    // scores (log2 domain) + online softmax with defer-max.
    float sc[4][4], p_[4][4], mt[4], ts[4];
#pragma unroll
    for (int j = 0; j < 4; j++)
#pragma unroll
      for (int r = 0; r < 4; r++)
        sc[j][r] = __builtin_fmaf(s[j][r], SCL2, bias[j][r]);
#pragma unroll
    for (int r = 0; r < 4; r++) {
      mt[r] = fmaxf(fmaxf(sc[0][r], sc[1][r]), fmaxf(sc[2][r], sc[3][r]));
#pragma unroll
      for (int msk = 1; msk < 16; msk <<= 1)
        mt[r] = fmaxf(mt[r], __shfl_xor(mt[r], msk));
      // defer-max: only rescale when tile max exceeds running max by > THR
      if (mt[r] > m[r] + THR) {
        const float rs = __builtin_amdgcn_exp2f(m[r] - mt[r]);
        m[r] = mt[r];
#pragma unroll
        for (int j = 0; j < 4; j++) Oacc[j][r] *= rs;
        lsum[r] *= rs;
      }
#pragma unroll
      for (int j = 0; j < 4; j++)
        p_[j][r] = __builtin_amdgcn_exp2f(sc[j][r] - m[r]);
      ts[r] = p_[0][r] + p_[1][r] + p_[2][r] + p_[3][r];
#pragma unroll
      for (int msk = 1; msk < 16; msk <<= 1)
        ts[r] += __shfl_xor(ts[r], msk);
      lsum[r] += ts[r];
    }

    // P -> bf16 -> wave-private swizzled LDS (A-fragment relayout)
    unsigned short* Pw = &Ps[w][0];
#pragma unroll
    for (int j = 0; j < 4; j++)
#pragma unroll
      for (int r = 0; r < 4; r++) {
        int row = quad * 4 + r;
        int col = j * 16 + r16;
        int chunk = col >> 3;
        Pw[row * KT + ((chunk ^ (row & 7)) * 8 + (col & 7))] = f2bf(p_[j][r]);
      }

    // O += P @ V   (B-frags from vT tile: rows = d, cols = keys)
#pragma unroll
    for (int ks = 0; ks < 2; ks++) {
      bf16x8 pA = *(const bf16x8*)&Pw[r16 * KT + ((ks * 4 + quad) ^ sw) * 8];
      bf16x8 vB[4];
#pragma unroll
      for (int j = 0; j < 4; j++)
        vB[j] = *(const bf16x8*)&Vs[cur][(j * 16 + r16) * KT + ((ks * 4 + quad) ^ sw) * 8];
#pragma unroll
      for (int j = 0; j < 4; j++)
        Oacc[j] = __builtin_amdgcn_mfma_f32_16x16x32_bf16(pA, vB[j], Oacc[j], 0, 0, 0);
    }

    __syncthreads();    // drains prefetch vmcnt; next tile ready
    cur ^= 1;
  }

  // epilogue: O / l -> bf16
#pragma unroll
  for (int r = 0; r < 4; r++) {
    const float inv = 1.0f / lsum[r];
    const long rowg = (long)b_ * SEQ + q0 + w * 16 + quad * 4 + r;
#pragma unroll
    for (int j = 0; j < 4; j++)
      O[rowg * DIM + h_ * DH + j * 16 + r16] = f2bf(Oacc[j][r] * inv);
  }
}

// ---------------------------------------------------------------------------
// LayerNorm: one block (256 thr) per row of 1024 fp32 -> bf16 out
// ---------------------------------------------------------------------------
__global__ void k_layernorm(const float* __restrict__ x, const float* __restrict__ g,
                            const float* __restrict__ b, unsigned short* __restrict__ out)
{
  const int row = blockIdx.x;
  const int t = threadIdx.x;
  float4 v = ((const float4*)(x + (long)row * DIM))[t];
  float s = v.x + v.y + v.z + v.w;
  float q = v.x * v.x + v.y * v.y + v.z * v.z + v.w * v.w;
#pragma unroll
  for (int off = 32; off > 0; off >>= 1) {
    s += __shfl_down(s, off);
    q += __shfl_down(q, off);
  }
  __shared__ float shs[4], shq[4];
  if ((t & 63) == 0) { shs[t >> 6] = s; shq[t >> 6] = q; }
  __syncthreads();
  s = shs[0] + shs[1] + shs[2] + shs[3];
  q = shq[0] + shq[1] + shq[2] + shq[3];
  const float mu  = s * (1.0f / DIM);
  const float var = q * (1.0f / DIM) - mu * mu;
  const float rs  = rsqrtf(var + 1e-5f);
  float4 gg = ((const float4*)g)[t];
  float4 bb = ((const float4*)b)[t];
  ushort4 o;
  o.x = f2bf((v.x - mu) * rs * gg.x + bb.x);
  o.y = f2bf((v.y - mu) * rs * gg.y + bb.y);
  o.z = f2bf((v.z - mu) * rs * gg.z + bb.z);
  o.w = f2bf((v.w - mu) * rs * gg.w + bb.w);
  ((ushort4*)out)[(long)row * (DIM / 4) + t] = o;
}

// ---------------------------------------------------------------------------
// rpb fp32 -> bf16, pre-scaled by log2(e). 16384 blocks x 256 thr x 1 float4.
// ---------------------------------------------------------------------------
__global__ void k_cvtrpb(const float* __restrict__ src, unsigned short* __restrict__ dst)
{
  const long i = ((long)blockIdx.x * 256 + threadIdx.x) * 4;
  float4 v = *(const float4*)(src + i);
  ushort4 o;
  o.x = f2bf(v.x * 1.44269504f);
  o.y = f2bf(v.y * 1.44269504f);
  o.z = f2bf(v.z * 1.44269504f);
  o.w = f2bf(v.w * 1.44269504f);
  *(ushort4*)(dst + i) = o;
}

// ---------------------------------------------------------------------------
// Fused weight transpose+convert for all 4 weights of one layer.
// w[K][N] fp32 -> wT[N][K] bf16, 64x64 tiles, block (64,4).
// ---------------------------------------------------------------------------
__global__ void k_wtrans_all(const float* __restrict__ wqkv, const float* __restrict__ wout,
                             const float* __restrict__ w1,   const float* __restrict__ w2,
                             unsigned short* __restrict__ wTqkv, unsigned short* __restrict__ wTout,
                             unsigned short* __restrict__ wT1,   unsigned short* __restrict__ wT2)
{
  __shared__ unsigned short tile[64][65];
  int t = blockIdx.x;
  const float* w; unsigned short* wT; int K, N;
  if (t < 768)        {            w = wqkv; wT = wTqkv; K = DIM; N = 3 * DIM; }
  else if (t < 1024)  { t -= 768;  w = wout; wT = wTout; K = DIM; N = DIM; }
  else if (t < 2048)  { t -= 1024; w = w1;   wT = wT1;   K = DIM; N = FF; }
  else                { t -= 2048; w = w2;   wT = wT2;   K = FF;  N = DIM; }
  const int nt = N / 64;
  const int n0 = (t % nt) * 64, k0 = (t / nt) * 64;
  const int tx = threadIdx.x, ty = threadIdx.y;
#pragma unroll
  for (int i = 0; i < 16; i++)
    tile[ty + 4 * i][tx] = f2bf(w[(long)(k0 + ty + 4 * i) * N + n0 + tx]);
  __syncthreads();
#pragma unroll
  for (int i = 0; i < 16; i++)
    wT[(long)(n0 + ty + 4 * i) * K + k0 + tx] = tile[tx][ty + 4 * i];
}

// ---------------------------------------------------------------------------
// V transpose: qkv[b, n, 2*DIM + h*64 + d] (bf16) -> vT[(b*16+h)][d][n]
// ---------------------------------------------------------------------------
__global__ void k_vtrans(const unsigned short* __restrict__ qkv, unsigned short* __restrict__ vT)
{
  __shared__ unsigned short tile[64][65];
  const int z = blockIdx.z;
  const int b_ = z >> 4, h_ = z & 15;
  const int n0 = blockIdx.x * 64;
  const int tx = threadIdx.x, ty = threadIdx.y;
  const unsigned short* src = qkv + (long)b_ * SEQ * (3 * DIM) + 2 * DIM + h_ * DH;
#pragma unroll
  for (int i = 0; i < 16; i++)
    tile[ty + 4 * i][tx] = src[(long)(n0 + ty + 4 * i) * (3 * DIM) + tx];
  __syncthreads();
  unsigned short* dst = vT + (long)z * DH * SEQ;
#pragma unroll
  for (int i = 0; i < 16; i++)
    dst[(long)(ty + 4 * i) * SEQ + n0 + tx] = tile[tx][ty + 4 * i];
}

// ---------------------------------------------------------------------------
extern "C" void kernel_launch(void* const* d_in, const int* in_sizes, int n_in,
                              void* d_out, int out_size, void* d_ws, size_t ws_size,
                              hipStream_t stream)
{
  const float* x0   = (const float*)d_in[0];
  const float* rpb  = (const float*)d_in[1];
  const float* ln1g = (const float*)d_in[2];
  const float* ln1b = (const float*)d_in[3];
  const float* wqkv = (const float*)d_in[4];
  const float* wout = (const float*)d_in[5];
  const float* bout = (const float*)d_in[6];
  const float* ln2g = (const float*)d_in[7];
  const float* ln2b = (const float*)d_in[8];
  const float* w1   = (const float*)d_in[9];
  const float* b1   = (const float*)d_in[10];
  const float* w2   = (const float*)d_in[11];
  const float* b2   = (const float*)d_in[12];
  float* x = (float*)d_out;   // running residual stream (fp32), doubles as output

  // workspace layout (~117 MB)
  char* p = (char*)d_ws;
  auto alloc = [&](size_t n) { char* r = p; p += (n + 255) & ~(size_t)255; return r; };
  unsigned short* wTqkv = (unsigned short*)alloc((size_t)3 * DIM * DIM * 2);
  unsigned short* wTout = (unsigned short*)alloc((size_t)DIM * DIM * 2);
  unsigned short* wT1   = (unsigned short*)alloc((size_t)FF * DIM * 2);
  unsigned short* wT2   = (unsigned short*)alloc((size_t)DIM * FF * 2);
  unsigned short* hbuf  = (unsigned short*)alloc((size_t)ROWS * DIM * 2);
  unsigned short* qkvb  = (unsigned short*)alloc((size_t)ROWS * 3 * DIM * 2);
  unsigned short* vTb   = (unsigned short*)alloc((size_t)BATCH * HEADS * DH * SEQ * 2);
  unsigned short* obuf  = (unsigned short*)alloc((size_t)ROWS * DIM * 2);
  unsigned short* ffnb  = (unsigned short*)alloc((size_t)ROWS * FF * 2);
  unsigned short* rpbh  = (unsigned short*)alloc((size_t)HEADS * SEQ * SEQ * 2);
  float*          pbuf  = (float*)alloc((size_t)2 * ROWS * DIM * 4);   // split-K partials

  hipMemcpyAsync(x, x0, (size_t)ROWS * DIM * 4, hipMemcpyDeviceToDevice, stream);

  // one-time: rpb fp32 -> bf16 * log2e
  k_cvtrpb<<<dim3(16384), 256, 0, stream>>>(rpb, rpbh);

  const dim3 tb(64, 4);
  const long PS = (long)ROWS * DIM;   // partial stride
  for (int l = 0; l < DEPTH; l++) {
    const float* Wqkv = wqkv + (size_t)l * DIM * 3 * DIM;
    const float* Wout = wout + (size_t)l * DIM * DIM;
    const float* W1   = w1   + (size_t)l * DIM * FF;
    const float* W2   = w2   + (size_t)l * FF * DIM;

    // all 4 weight transposes in one launch (3072 tiles)
    k_wtrans_all<<<dim3(3072), tb, 0, stream>>>(Wqkv, Wout, W1, W2,
                                                wTqkv, wTout, wT1, wT2);

    // ---- attention ----
    k_layernorm<<<ROWS, 256, 0, stream>>>(x, ln1g + l * DIM, ln1b + l * DIM, hbuf);

    // qkv: 64x64 tiles -> (32,48) = 1536 blocks (6/CU)
    gemm_kernel<64, 64, 0, 1, 4><<<dim3(ROWS / 64, 3 * DIM / 64), 256, 0, stream>>>(
        hbuf, DIM, wTqkv, DIM, qkvb, nullptr, 3 * DIM, nullptr, DIM, 0);

    k_vtrans<<<dim3(SEQ / 64, 1, BATCH * HEADS), tb, 0, stream>>>(qkvb, vTb);

    // fused scores+bias+softmax+PV -> obuf   (512 blocks)
    k_flashattn<<<dim3(SEQ / 64, 1, BATCH * HEADS), 256, 0, stream>>>(
        qkvb, vTb, rpbh, obuf);

    // out_proj: 64x64, split-K=2 -> (32,16,2) = 1024 blocks (4/CU), fp32 partials
    gemm_kernel<64, 64, 4, 2, 4><<<dim3(ROWS / 64, DIM / 64, 2), 256, 0, stream>>>(
        obuf, DIM, wTout, DIM, nullptr, pbuf, DIM, nullptr, DIM, PS);
    k_reduce2<<<dim3(ROWS * DIM / 1024), 256, 0, stream>>>(x, pbuf, bout + l * DIM);

    // ---- FFN ----
    k_layernorm<<<ROWS, 256, 0, stream>>>(x, ln2g + l * DIM, ln2b + l * DIM, hbuf);

    // FFN1: 64x64 -> (32,64) = 2048 blocks (8/CU)
    gemm_kernel<64, 64, 3, 1, 4><<<dim3(ROWS / 64, FF / 64), 256, 0, stream>>>(
        hbuf, DIM, wT1, DIM, ffnb, nullptr, FF, b1 + l * FF, DIM, 0);

    // FFN2: 64x64, split-K=2 over K=4096 -> 1024 blocks (4/CU), fp32 partials
    gemm_kernel<64, 64, 4, 2, 4><<<dim3(ROWS / 64, DIM / 64, 2), 256, 0, stream>>>(
        ffnb, FF, wT2, FF, nullptr, pbuf, DIM, nullptr, FF, PS);
    k_reduce2<<<dim3(ROWS * DIM / 1024), 256, 0, stream>>>(x, pbuf, b2 + l * DIM);
  }
}

// Round 5
// 1201.391 us; speedup vs baseline: 1.3147x; 1.0635x over previous
//
#include <hip/hip_runtime.h>
#include <stdint.h>

#define DIM   1024
#define DEPTH 6
#define HEADS 16
#define FF    4096
#define SEQ   1024
#define BATCH 2
#define ROWS  (BATCH*SEQ)   // 2048
#define DH    64            // head dim

typedef __bf16 bf16x8 __attribute__((ext_vector_type(8)));
typedef float  f32x4  __attribute__((ext_vector_type(4)));

__device__ __forceinline__ unsigned short f2bf(float f) {
  unsigned int u = __builtin_bit_cast(unsigned int, f);
  u += 0x7fff + ((u >> 16) & 1);          // round-to-nearest-even
  return (unsigned short)(u >> 16);
}
__device__ __forceinline__ float bf2f(unsigned short h) {
  unsigned int u = ((unsigned int)h) << 16;
  return __builtin_bit_cast(float, u);
}

// async global->LDS, 16 bytes per lane. LDS dest must be uniform-base + lane*16.
__device__ __forceinline__ void async_load16(const void* g, void* l) {
  __builtin_amdgcn_global_load_lds(
      (const __attribute__((address_space(1))) unsigned int*)g,
      (__attribute__((address_space(3))) unsigned int*)l, 16, 0, 0);
}

// ---------------------------------------------------------------------------
// GEMM: C[M,N] = A[M,K] @ B^T  where B is stored [N][K] (bf16, K contiguous).
// BK=64, 256 threads (4 waves). 16x16x32 bf16 MFMA.
// LDS tiles XOR-swizzled: 16B chunk c of row r lives at chunk (c ^ (r&7)).
//
// Structure: single-buffered, 2 barriers per K-step. Throughput = per-wave
// MFMA density (64x128 tile: 16 MFMA/wave/K-step) x blocks/CU (>=3).
// 64x128 = 24 KB LDS -> 6 blocks/CU LDS-limit.
//
// SPLITK>1: blockIdx.z = K-split index; EPI==4 stores fp32 partials to
// Cf[z*pstride + idx] (plain streaming stores; reduce kernel sums).
//
// EPI: 0 = store bf16
//      3 = store bf16 of gelu(acc + bias1[n])                 (FFN mid)
//      4 = store fp32 partial (split-K)
// ---------------------------------------------------------------------------
template<int BM, int BN, int EPI, int SPLITK, int MINW>
__global__ void __launch_bounds__(256, MINW)
gemm_kernel(const unsigned short* __restrict__ A, long lda,
            const unsigned short* __restrict__ B, long ldb,
            unsigned short* __restrict__ Cb, float* __restrict__ Cf, long ldc,
            const float* __restrict__ bias1, int K, long pstride)
{
  constexpr int BK = 64;                    // 8 chunks of 16B per row
  const int z = blockIdx.z;
  const int Kloc = K / SPLITK;
  const long kbase = (long)z * Kloc;

  __shared__ unsigned short As[BM * BK];
  __shared__ unsigned short Bs[BN * BK];

  const int tid  = threadIdx.x;
  const int row0 = blockIdx.x * BM;
  const int col0 = blockIdx.y * BN;

  constexpr int WGN = 2;                    // waves along N
  constexpr int WGM = 2;                    // waves along M
  constexpr int WTM = BM / WGM;             // wave tile M
  constexpr int WTN = BN / WGN;             // wave tile N
  constexpr int ITM = WTM / 16;
  constexpr int ITN = WTN / 16;

  const int w = tid >> 6, l = tid & 63;
  const int quad = l >> 4, r16 = l & 15;
  const int wm = (w / WGN) * WTM;
  const int wn = (w % WGN) * WTN;
  const int sw = r16 & 7;                   // read-side XOR swizzle key

  f32x4 acc[ITM][ITN] = {};

  constexpr int APASS = (BM * 8) / 256;     // 16B chunks per thread for A tile
  constexpr int BPASS = (BN * 8) / 256;

  const unsigned short* Ag = A + (long)row0 * lda;
  const unsigned short* Bg = B + (long)col0 * ldb;

  for (long k0 = kbase; k0 < kbase + Kloc; k0 += BK) {
#pragma unroll
    for (int p = 0; p < APASS; p++) {
      int flat = p * 256 + tid;
      int r = flat >> 3, cl = flat & 7;
      int cg = cl ^ (r & 7);                // fetch the chunk that belongs at slot cl
      async_load16(Ag + (long)r * lda + k0 + cg * 8, &As[flat * 8]);
    }
#pragma unroll
    for (int p = 0; p < BPASS; p++) {
      int flat = p * 256 + tid;
      int r = flat >> 3, cl = flat & 7;
      int cg = cl ^ (r & 7);
      async_load16(Bg + (long)r * ldb + k0 + cg * 8, &Bs[flat * 8]);
    }
    __syncthreads();   // drains vmcnt: LDS now holds the tiles
#pragma unroll
    for (int ks = 0; ks < 2; ks++) {
      const int c = ks * 4 + quad;          // logical 16B chunk index
      bf16x8 af[ITM], bfr[ITN];
#pragma unroll
      for (int i = 0; i < ITM; i++)
        af[i] = *(const bf16x8*)&As[(wm + i * 16 + r16) * BK + (c ^ sw) * 8];
#pragma unroll
      for (int j = 0; j < ITN; j++)
        bfr[j] = *(const bf16x8*)&Bs[(wn + j * 16 + r16) * BK + (c ^ sw) * 8];
#pragma unroll
      for (int i = 0; i < ITM; i++)
#pragma unroll
        for (int j = 0; j < ITN; j++)
          acc[i][j] = __builtin_amdgcn_mfma_f32_16x16x32_bf16(af[i], bfr[j], acc[i][j], 0, 0, 0);
    }
    __syncthreads();
  }

  // epilogue: C/D layout row = quad*4 + reg, col = lane&15
#pragma unroll
  for (int i = 0; i < ITM; i++) {
#pragma unroll
    for (int j = 0; j < ITN; j++) {
      const int rr = row0 + wm + i * 16 + quad * 4;
      const int cc = col0 + wn + j * 16 + r16;
#pragma unroll
      for (int r = 0; r < 4; r++) {
        const long idx = (long)(rr + r) * ldc + cc;
        float v = acc[i][j][r];
        if constexpr (EPI == 0) {
          Cb[idx] = f2bf(v);
        } else if constexpr (EPI == 3) {
          v += bias1[cc];
          float gl = 0.5f * v * (1.0f + erff(v * 0.70710678118654752f));
          Cb[idx] = f2bf(gl);
        } else if constexpr (EPI == 4) {
          Cf[(long)z * pstride + idx] = v;
        }
      }
    }
  }
}

// ---------------------------------------------------------------------------
// Fused split-K reduce + residual add + (optional) LayerNorm.
// One block per row. x[row] += sum(partials) + bias; if DOLN, LN(x) -> out.
// ---------------------------------------------------------------------------
template<int NP, bool DOLN>
__global__ void k_reduce_ln(float* __restrict__ x, const float* __restrict__ pbuf,
                            const float* __restrict__ bias,
                            const float* __restrict__ g, const float* __restrict__ b,
                            unsigned short* __restrict__ out)
{
  const int row = blockIdx.x;
  const int t = threadIdx.x;
  const long i = (long)row * (DIM / 4) + t;   // float4 index
  float4 v = ((float4*)x)[i];
#pragma unroll
  for (int p = 0; p < NP; p++) {
    float4 pp = ((const float4*)(pbuf + (long)p * ROWS * DIM))[i];
    v.x += pp.x; v.y += pp.y; v.z += pp.z; v.w += pp.w;
  }
  float4 bb = ((const float4*)bias)[t];
  v.x += bb.x; v.y += bb.y; v.z += bb.z; v.w += bb.w;
  ((float4*)x)[i] = v;

  if constexpr (DOLN) {
    float s = v.x + v.y + v.z + v.w;
    float q = v.x * v.x + v.y * v.y + v.z * v.z + v.w * v.w;
#pragma unroll
    for (int off = 32; off > 0; off >>= 1) {
      s += __shfl_down(s, off);
      q += __shfl_down(q, off);
    }
    __shared__ float shs[4], shq[4];
    if ((t & 63) == 0) { shs[t >> 6] = s; shq[t >> 6] = q; }
    __syncthreads();
    s = shs[0] + shs[1] + shs[2] + shs[3];
    q = shq[0] + shq[1] + shq[2] + shq[3];
    const float mu  = s * (1.0f / DIM);
    const float var = q * (1.0f / DIM) - mu * mu;
    const float rs  = rsqrtf(var + 1e-5f);
    float4 gg = ((const float4*)g)[t];
    float4 bv = ((const float4*)b)[t];
    ushort4 o;
    o.x = f2bf((v.x - mu) * rs * gg.x + bv.x);
    o.y = f2bf((v.y - mu) * rs * gg.y + bv.y);
    o.z = f2bf((v.z - mu) * rs * gg.z + bv.z);
    o.w = f2bf((v.w - mu) * rs * gg.w + bv.w);
    ((ushort4*)out)[i] = o;
  }
}

// ---------------------------------------------------------------------------
// Fused flash attention (log2-domain softmax, defer-max rescale).
// Grid: (SEQ/64, 1, BATCH*HEADS), 256 threads (4 waves), 48 KB LDS.
// launch_bounds(256,3): 3 blocks/CU (LDS allows 3).
// ---------------------------------------------------------------------------
__global__ void __launch_bounds__(256, 3)
k_flashattn(const unsigned short* __restrict__ qkv,  // [b][n][3*DIM]
            const unsigned short* __restrict__ vT,   // [b*16+h][d][n]
            const unsigned short* __restrict__ rpbh, // [h][n][n] bf16, *log2e
            unsigned short* __restrict__ O)          // [b][n][DIM]
{
  constexpr int QT = 64;          // q rows per block
  constexpr int KT = 64;          // keys per tile
  constexpr int NT = SEQ / KT;    // 16 tiles
  constexpr float SCL2 = 0.18033688f;   // 0.125 * log2(e)
  constexpr float THR  = 11.5415603f;   // 8 * log2(e)

  __shared__ __align__(16) unsigned short Qs[QT * DH];       // 8 KB
  __shared__ __align__(16) unsigned short Ks[2][KT * DH];    // 16 KB
  __shared__ __align__(16) unsigned short Vs[2][DH * KT];    // 16 KB
  __shared__ __align__(16) unsigned short Ps[4][16 * KT];    // 8 KB (per-wave)

  const int z = blockIdx.z;
  const int b_ = z >> 4, h_ = z & 15;
  const int q0 = blockIdx.x * QT;
  const int tid = threadIdx.x;
  const int w = tid >> 6, l = tid & 63;
  const int quad = l >> 4, r16 = l & 15;
  const int sw = r16 & 7;

  const unsigned short* Qg = qkv + (long)b_ * SEQ * (3 * DIM) + h_ * DH;
  const unsigned short* Kg = Qg + DIM;
  const unsigned short* Vg = vT + (long)z * DH * SEQ;
  const unsigned short* Rg = rpbh + (long)h_ * SEQ * SEQ + (long)q0 * SEQ;

  auto stageKV = [&](int buf, int kt) {
#pragma unroll
    for (int p = 0; p < 2; p++) {
      int flat = p * 256 + tid;
      int r = flat >> 3, cl = flat & 7, cg = cl ^ (r & 7);
      async_load16(Kg + (long)(kt * KT + r) * (3 * DIM) + cg * 8, &Ks[buf][flat * 8]);
    }
#pragma unroll
    for (int p = 0; p < 2; p++) {
      int flat = p * 256 + tid;
      int r = flat >> 3, cl = flat & 7, cg = cl ^ (r & 7);
      async_load16(Vg + (long)r * SEQ + kt * KT + cg * 8, &Vs[buf][flat * 8]);
    }
  };

  // stage Q + first K/V
#pragma unroll
  for (int p = 0; p < 2; p++) {
    int flat = p * 256 + tid;
    int r = flat >> 3, cl = flat & 7, cg = cl ^ (r & 7);
    async_load16(Qg + (long)(q0 + r) * (3 * DIM) + cg * 8, &Qs[flat * 8]);
  }
  stageKV(0, 0);
  __syncthreads();

  // Q fragments (held in registers for the whole kernel)
  bf16x8 qA[2];
#pragma unroll
  for (int ks = 0; ks < 2; ks++)
    qA[ks] = *(const bf16x8*)&Qs[(w * 16 + r16) * DH + (((ks * 4 + quad)) ^ sw) * 8];

  f32x4 Oacc[4] = {};
  float m[4], lsum[4];
#pragma unroll
  for (int r = 0; r < 4; r++) { m[r] = -1e30f; lsum[r] = 0.0f; }

  int cur = 0;
  for (int kt = 0; kt < NT; kt++) {
    if (kt + 1 < NT) stageKV(cur ^ 1, kt + 1);   // async prefetch next tile

    // rpb bias loads (bf16, log2-scaled) — issued before MFMAs so they overlap
    float bias[4][4];
    const unsigned short* Rt = Rg + kt * KT;
#pragma unroll
    for (int j = 0; j < 4; j++)
#pragma unroll
      for (int r = 0; r < 4; r++)
        bias[j][r] = bf2f(Rt[(long)(w * 16 + quad * 4 + r) * SEQ + j * 16 + r16]);

    // S = Q @ K^T  (rows = q, cols = keys of this tile)
    f32x4 s[4] = {};
#pragma unroll
    for (int ks = 0; ks < 2; ks++) {
      bf16x8 kB[4];
#pragma unroll
      for (int j = 0; j < 4; j++)
        kB[j] = *(const bf16x8*)&Ks[cur][(j * 16 + r16) * DH + ((ks * 4 + quad) ^ sw) * 8];
#pragma unroll
      for (int j = 0; j < 4; j++)
        s[j] = __builtin_amdgcn_mfma_f32_16x16x32_bf16(qA[ks], kB[j], s[j], 0, 0, 0);
    }

    // scores (log2 domain) + online softmax with defer-max.
    float sc[4][4], p_[4][4], mt[4], ts[4];
#pragma unroll
    for (int j = 0; j < 4; j++)
#pragma unroll
      for (int r = 0; r < 4; r++)
        sc[j][r] = __builtin_fmaf(s[j][r], SCL2, bias[j][r]);
#pragma unroll
    for (int r = 0; r < 4; r++) {
      mt[r] = fmaxf(fmaxf(sc[0][r], sc[1][r]), fmaxf(sc[2][r], sc[3][r]));
#pragma unroll
      for (int msk = 1; msk < 16; msk <<= 1)
        mt[r] = fmaxf(mt[r], __shfl_xor(mt[r], msk));
      // defer-max: only rescale when tile max exceeds running max by > THR
      if (mt[r] > m[r] + THR) {
        const float rs = __builtin_amdgcn_exp2f(m[r] - mt[r]);
        m[r] = mt[r];
#pragma unroll
        for (int j = 0; j < 4; j++) Oacc[j][r] *= rs;
        lsum[r] *= rs;
      }
#pragma unroll
      for (int j = 0; j < 4; j++)
        p_[j][r] = __builtin_amdgcn_exp2f(sc[j][r] - m[r]);
      ts[r] = p_[0][r] + p_[1][r] + p_[2][r] + p_[3][r];
#pragma unroll
      for (int msk = 1; msk < 16; msk <<= 1)
        ts[r] += __shfl_xor(ts[r], msk);
      lsum[r] += ts[r];
    }

    // P -> bf16 -> wave-private swizzled LDS (A-fragment relayout)
    unsigned short* Pw = &Ps[w][0];
#pragma unroll
    for (int j = 0; j < 4; j++)
#pragma unroll
      for (int r = 0; r < 4; r++) {
        int row = quad * 4 + r;
        int col = j * 16 + r16;
        int chunk = col >> 3;
        Pw[row * KT + ((chunk ^ (row & 7)) * 8 + (col & 7))] = f2bf(p_[j][r]);
      }

    // O += P @ V   (B-frags from vT tile: rows = d, cols = keys)
#pragma unroll
    for (int ks = 0; ks < 2; ks++) {
      bf16x8 pA = *(const bf16x8*)&Pw[r16 * KT + ((ks * 4 + quad) ^ sw) * 8];
      bf16x8 vB[4];
#pragma unroll
      for (int j = 0; j < 4; j++)
        vB[j] = *(const bf16x8*)&Vs[cur][(j * 16 + r16) * KT + ((ks * 4 + quad) ^ sw) * 8];
#pragma unroll
      for (int j = 0; j < 4; j++)
        Oacc[j] = __builtin_amdgcn_mfma_f32_16x16x32_bf16(pA, vB[j], Oacc[j], 0, 0, 0);
    }

    __syncthreads();    // drains prefetch vmcnt; next tile ready
    cur ^= 1;
  }

  // epilogue: O / l -> bf16
#pragma unroll
  for (int r = 0; r < 4; r++) {
    const float inv = 1.0f / lsum[r];
    const long rowg = (long)b_ * SEQ + q0 + w * 16 + quad * 4 + r;
#pragma unroll
    for (int j = 0; j < 4; j++)
      O[rowg * DIM + h_ * DH + j * 16 + r16] = f2bf(Oacc[j][r] * inv);
  }
}

// ---------------------------------------------------------------------------
// LayerNorm: one block (256 thr) per row of 1024 fp32 -> bf16 out.
// Only used for layer-0 LN1 (later LNs are fused into k_reduce_ln).
// ---------------------------------------------------------------------------
__global__ void k_layernorm(const float* __restrict__ x, const float* __restrict__ g,
                            const float* __restrict__ b, unsigned short* __restrict__ out)
{
  const int row = blockIdx.x;
  const int t = threadIdx.x;
  float4 v = ((const float4*)(x + (long)row * DIM))[t];
  float s = v.x + v.y + v.z + v.w;
  float q = v.x * v.x + v.y * v.y + v.z * v.z + v.w * v.w;
#pragma unroll
  for (int off = 32; off > 0; off >>= 1) {
    s += __shfl_down(s, off);
    q += __shfl_down(q, off);
  }
  __shared__ float shs[4], shq[4];
  if ((t & 63) == 0) { shs[t >> 6] = s; shq[t >> 6] = q; }
  __syncthreads();
  s = shs[0] + shs[1] + shs[2] + shs[3];
  q = shq[0] + shq[1] + shq[2] + shq[3];
  const float mu  = s * (1.0f / DIM);
  const float var = q * (1.0f / DIM) - mu * mu;
  const float rs  = rsqrtf(var + 1e-5f);
  float4 gg = ((const float4*)g)[t];
  float4 bb = ((const float4*)b)[t];
  ushort4 o;
  o.x = f2bf((v.x - mu) * rs * gg.x + bb.x);
  o.y = f2bf((v.y - mu) * rs * gg.y + bb.y);
  o.z = f2bf((v.z - mu) * rs * gg.z + bb.z);
  o.w = f2bf((v.w - mu) * rs * gg.w + bb.w);
  ((ushort4*)out)[(long)row * (DIM / 4) + t] = o;
}

// ---------------------------------------------------------------------------
// rpb fp32 -> bf16, pre-scaled by log2(e). 16384 blocks x 256 thr x 1 float4.
// ---------------------------------------------------------------------------
__global__ void k_cvtrpb(const float* __restrict__ src, unsigned short* __restrict__ dst)
{
  const long i = ((long)blockIdx.x * 256 + threadIdx.x) * 4;
  float4 v = *(const float4*)(src + i);
  ushort4 o;
  o.x = f2bf(v.x * 1.44269504f);
  o.y = f2bf(v.y * 1.44269504f);
  o.z = f2bf(v.z * 1.44269504f);
  o.w = f2bf(v.w * 1.44269504f);
  *(ushort4*)(dst + i) = o;
}

// ---------------------------------------------------------------------------
// Fused weight transpose+convert for all 4 weights of one layer.
// w[K][N] fp32 -> wT[N][K] bf16, 64x64 tiles, block (64,4).
// ---------------------------------------------------------------------------
__global__ void k_wtrans_all(const float* __restrict__ wqkv, const float* __restrict__ wout,
                             const float* __restrict__ w1,   const float* __restrict__ w2,
                             unsigned short* __restrict__ wTqkv, unsigned short* __restrict__ wTout,
                             unsigned short* __restrict__ wT1,   unsigned short* __restrict__ wT2)
{
  __shared__ unsigned short tile[64][65];
  int t = blockIdx.x;
  const float* w; unsigned short* wT; int K, N;
  if (t < 768)        {            w = wqkv; wT = wTqkv; K = DIM; N = 3 * DIM; }
  else if (t < 1024)  { t -= 768;  w = wout; wT = wTout; K = DIM; N = DIM; }
  else if (t < 2048)  { t -= 1024; w = w1;   wT = wT1;   K = DIM; N = FF; }
  else                { t -= 2048; w = w2;   wT = wT2;   K = FF;  N = DIM; }
  const int nt = N / 64;
  const int n0 = (t % nt) * 64, k0 = (t / nt) * 64;
  const int tx = threadIdx.x, ty = threadIdx.y;
#pragma unroll
  for (int i = 0; i < 16; i++)
    tile[ty + 4 * i][tx] = f2bf(w[(long)(k0 + ty + 4 * i) * N + n0 + tx]);
  __syncthreads();
#pragma unroll
  for (int i = 0; i < 16; i++)
    wT[(long)(n0 + ty + 4 * i) * K + k0 + tx] = tile[tx][ty + 4 * i];
}

// ---------------------------------------------------------------------------
// V transpose: qkv[b, n, 2*DIM + h*64 + d] (bf16) -> vT[(b*16+h)][d][n]
// ---------------------------------------------------------------------------
__global__ void k_vtrans(const unsigned short* __restrict__ qkv, unsigned short* __restrict__ vT)
{
  __shared__ unsigned short tile[64][65];
  const int z = blockIdx.z;
  const int b_ = z >> 4, h_ = z & 15;
  const int n0 = blockIdx.x * 64;
  const int tx = threadIdx.x, ty = threadIdx.y;
  const unsigned short* src = qkv + (long)b_ * SEQ * (3 * DIM) + 2 * DIM + h_ * DH;
#pragma unroll
  for (int i = 0; i < 16; i++)
    tile[ty + 4 * i][tx] = src[(long)(n0 + ty + 4 * i) * (3 * DIM) + tx];
  __syncthreads();
  unsigned short* dst = vT + (long)z * DH * SEQ;
#pragma unroll
  for (int i = 0; i < 16; i++)
    dst[(long)(ty + 4 * i) * SEQ + n0 + tx] = tile[tx][ty + 4 * i];
}

// ---------------------------------------------------------------------------
extern "C" void kernel_launch(void* const* d_in, const int* in_sizes, int n_in,
                              void* d_out, int out_size, void* d_ws, size_t ws_size,
                              hipStream_t stream)
{
  const float* x0   = (const float*)d_in[0];
  const float* rpb  = (const float*)d_in[1];
  const float* ln1g = (const float*)d_in[2];
  const float* ln1b = (const float*)d_in[3];
  const float* wqkv = (const float*)d_in[4];
  const float* wout = (const float*)d_in[5];
  const float* bout = (const float*)d_in[6];
  const float* ln2g = (const float*)d_in[7];
  const float* ln2b = (const float*)d_in[8];
  const float* w1   = (const float*)d_in[9];
  const float* b1   = (const float*)d_in[10];
  const float* w2   = (const float*)d_in[11];
  const float* b2   = (const float*)d_in[12];
  float* x = (float*)d_out;   // running residual stream (fp32), doubles as output

  // workspace layout (~127 MB)
  char* p = (char*)d_ws;
  auto alloc = [&](size_t n) { char* r = p; p += (n + 255) & ~(size_t)255; return r; };
  unsigned short* wTqkv = (unsigned short*)alloc((size_t)3 * DIM * DIM * 2);
  unsigned short* wTout = (unsigned short*)alloc((size_t)DIM * DIM * 2);
  unsigned short* wT1   = (unsigned short*)alloc((size_t)FF * DIM * 2);
  unsigned short* wT2   = (unsigned short*)alloc((size_t)DIM * FF * 2);
  unsigned short* hbuf  = (unsigned short*)alloc((size_t)ROWS * DIM * 2);
  unsigned short* qkvb  = (unsigned short*)alloc((size_t)ROWS * 3 * DIM * 2);
  unsigned short* vTb   = (unsigned short*)alloc((size_t)BATCH * HEADS * DH * SEQ * 2);
  unsigned short* obuf  = (unsigned short*)alloc((size_t)ROWS * DIM * 2);
  unsigned short* ffnb  = (unsigned short*)alloc((size_t)ROWS * FF * 2);
  unsigned short* rpbh  = (unsigned short*)alloc((size_t)HEADS * SEQ * SEQ * 2);
  float*          pbuf  = (float*)alloc((size_t)4 * ROWS * DIM * 4);   // split-K partials

  hipMemcpyAsync(x, x0, (size_t)ROWS * DIM * 4, hipMemcpyDeviceToDevice, stream);

  // one-time: rpb fp32 -> bf16 * log2e
  k_cvtrpb<<<dim3(16384), 256, 0, stream>>>(rpb, rpbh);

  const dim3 tb(64, 4);
  const long PS = (long)ROWS * DIM;   // partial stride
  for (int l = 0; l < DEPTH; l++) {
    const float* Wqkv = wqkv + (size_t)l * DIM * 3 * DIM;
    const float* Wout = wout + (size_t)l * DIM * DIM;
    const float* W1   = w1   + (size_t)l * DIM * FF;
    const float* W2   = w2   + (size_t)l * FF * DIM;

    // all 4 weight transposes in one launch (3072 tiles)
    k_wtrans_all<<<dim3(3072), tb, 0, stream>>>(Wqkv, Wout, W1, W2,
                                                wTqkv, wTout, wT1, wT2);

    // ---- attention ----
    if (l == 0)   // later layers: LN1 fused into FFN2's reduce of layer l-1
      k_layernorm<<<ROWS, 256, 0, stream>>>(x, ln1g, ln1b, hbuf);

    // qkv: 64x128 tiles -> (32,24) = 768 blocks (3/CU, 24KB LDS)
    gemm_kernel<64, 128, 0, 1, 4><<<dim3(ROWS / 64, 3 * DIM / 128), 256, 0, stream>>>(
        hbuf, DIM, wTqkv, DIM, qkvb, nullptr, 3 * DIM, nullptr, DIM, 0);

    k_vtrans<<<dim3(SEQ / 64, 1, BATCH * HEADS), tb, 0, stream>>>(qkvb, vTb);

    // fused scores+bias+softmax+PV -> obuf   (512 blocks, 3/CU)
    k_flashattn<<<dim3(SEQ / 64, 1, BATCH * HEADS), 256, 0, stream>>>(
        qkvb, vTb, rpbh, obuf);

    // out_proj: 64x64, split-K=2 -> 1024 blocks (4/CU), fp32 partials
    gemm_kernel<64, 64, 4, 2, 4><<<dim3(ROWS / 64, DIM / 64, 2), 256, 0, stream>>>(
        obuf, DIM, wTout, DIM, nullptr, pbuf, DIM, nullptr, DIM, PS);
    // x += partials + b_out, then LN2 -> hbuf (fused)
    k_reduce_ln<2, true><<<ROWS, 256, 0, stream>>>(
        x, pbuf, bout + l * DIM, ln2g + l * DIM, ln2b + l * DIM, hbuf);

    // ---- FFN ----
    // FFN1: 64x128 -> (32,32) = 1024 blocks (4/CU), gelu epilogue
    gemm_kernel<64, 128, 3, 1, 4><<<dim3(ROWS / 64, FF / 128), 256, 0, stream>>>(
        hbuf, DIM, wT1, DIM, ffnb, nullptr, FF, b1 + l * FF, DIM, 0);

    // FFN2: 64x128, split-K=4 over K=4096 -> (32,8,4) = 1024 blocks (4/CU)
    gemm_kernel<64, 128, 4, 4, 4><<<dim3(ROWS / 64, DIM / 128, 4), 256, 0, stream>>>(
        ffnb, FF, wT2, FF, nullptr, pbuf, DIM, nullptr, FF, PS);
    // x += partials + b2, then LN1 of next layer -> hbuf (fused), except last
    if (l < DEPTH - 1)
      k_reduce_ln<4, true><<<ROWS, 256, 0, stream>>>(
          x, pbuf, b2 + l * DIM, ln1g + (l + 1) * DIM, ln1b + (l + 1) * DIM, hbuf);
    else
      k_reduce_ln<4, false><<<ROWS, 256, 0, stream>>>(
          x, pbuf, b2 + l * DIM, nullptr, nullptr, nullptr);
  }
}